// Round 5
// baseline (574.135 us; speedup 1.0000x reference)
//
#include <hip/hip_runtime.h>
#include <hip/hip_bf16.h>

typedef __attribute__((ext_vector_type(8))) short bf16x8;
typedef __attribute__((ext_vector_type(4))) float f32x4;

#define MFMA(a,b,c) __builtin_amdgcn_mfma_f32_16x16x32_bf16((a),(b),(c),0,0,0)
#define WAVE_LDS_FENCE() do { asm volatile("s_waitcnt lgkmcnt(0)" ::: "memory"); \
                              __builtin_amdgcn_sched_barrier(0); } while (0)

static constexpr int NTOK = 8 * 8 * 56 * 56;   // 200704 tokens
static constexpr int NT   = 98;                // tokens per window
static constexpr int NWIN = 2048;              // total windows
static constexpr int NN   = NT * NT;           // 9604

// single-op bf16 convert (RNE), T12 recipe: no builtin on gfx950
__device__ __forceinline__ unsigned short f2bf(float f) {
  unsigned r;
  asm("v_cvt_pk_bf16_f32 %0, %1, %1" : "=v"(r) : "v"(f));
  return (unsigned short)r;
}
__device__ __forceinline__ unsigned f2bf2(float lo, float hi) {
  unsigned r;
  asm("v_cvt_pk_bf16_f32 %0, %1, %2" : "=v"(r) : "v"(lo), "v"(hi));
  return r;
}
__device__ __forceinline__ float bf2f(unsigned short s) {
  union { unsigned u; float f; } v; v.u = ((unsigned)s) << 16; return v.f;
}

// ---------------- K0: weight transpose + bf16 cast -------------------------
__global__ __launch_bounds__(256) void k0_prep(
    const float* __restrict__ qkv_w, const float* __restrict__ proj_w,
    const float* __restrict__ fc1_w, const float* __restrict__ fc2_w,
    unsigned short* __restrict__ qkvT, unsigned short* __restrict__ projT,
    unsigned short* __restrict__ fc1T, unsigned short* __restrict__ fc2T) {
  int idx = blockIdx.x * 256 + threadIdx.x;
  if (idx < 384 * 128) { int n = idx >> 7, k = idx & 127; qkvT[idx] = f2bf(qkv_w[k * 384 + n]); }
  if (idx < 128 * 128) { int n = idx >> 7, k = idx & 127; projT[idx] = f2bf(proj_w[k * 128 + n]); }
  if (idx < 512 * 128) { int n = idx >> 7, k = idx & 127; fc1T[idx] = f2bf(fc1_w[k * 512 + n]); }
  if (idx < 128 * 512) { int n = idx >> 9, k = idx & 511; fc2T[idx] = f2bf(fc2_w[k * 128 + n]); }
}

// ---------------- K0b: combined bias+mask table, bf16 ----------------------
__global__ __launch_bounds__(256) void k0b_cmb(
    const int* __restrict__ rel, const float* __restrict__ rpb,
    const float* __restrict__ mask, unsigned short* __restrict__ cmb) {
  int idx = blockIdx.x * 256 + threadIdx.x;
  if (idx >= 4 * 256 * NN) return;
  int h = idx / (256 * NN);
  int rem = idx - h * 256 * NN;
  int wb = rem / NN, r = rem - wb * NN;
  cmb[idx] = f2bf(rpb[rel[r] * 4 + h] + mask[(size_t)wb * NN + r]);
}

// ---------------- K1: LN1 + cyclic shift + window partition ----------------
__global__ __launch_bounds__(256) void k1_ln_part(
    const float* __restrict__ x, const float* __restrict__ g,
    const float* __restrict__ b, unsigned short* __restrict__ win) {
  int wv = threadIdx.x >> 6, lane = threadIdx.x & 63;
  int t = blockIdx.x * 4 + wv;
  int widx = t / NT, n = t - widx * NT;
  int bb = widx >> 8, wb = widx & 255;
  int dW = wb >> 6, hW = (wb >> 3) & 7, wW = wb & 7;
  int dr = n / 49, rem = n - dr * 49, hr = rem / 7, wr = rem - hr * 7;
  int ds = (dW * 2 + dr + 1) & 7;
  int hs = hW * 7 + hr + 3; if (hs >= 56) hs -= 56;
  int wsv = wW * 7 + wr + 3; if (wsv >= 56) wsv -= 56;
  size_t srow = ((size_t)(bb * 8 + ds) * 56 + hs) * 56 + wsv;
  const float2 v2 = *(const float2*)(x + srow * 128 + lane * 2);
  float s = v2.x + v2.y, ss = v2.x * v2.x + v2.y * v2.y;
#pragma unroll
  for (int m = 1; m < 64; m <<= 1) { s += __shfl_xor(s, m); ss += __shfl_xor(ss, m); }
  float mu = s * (1.f / 128.f);
  float var = ss * (1.f / 128.f) - mu * mu;
  float inv = __builtin_amdgcn_rsqf(var + 1e-5f);
  float g0 = g[lane * 2], g1 = g[lane * 2 + 1];
  float b0 = b[lane * 2], b1 = b[lane * 2 + 1];
  *(unsigned*)(win + (size_t)t * 128 + lane * 2) =
      f2bf2((v2.x - mu) * inv * g0 + b0, (v2.y - mu) * inv * g1 + b1);
}

// ---------------- K2: QKV GEMM, 512 thr / 256 rows, staged + prefetch ------
__global__ __launch_bounds__(512, 4) void k2_qkv(
    const unsigned short* __restrict__ win, const unsigned short* __restrict__ qkvT,
    const float* __restrict__ qkv_b,
    unsigned short* __restrict__ q, unsigned short* __restrict__ k,
    unsigned short* __restrict__ v) {
  __shared__ __align__(16) unsigned short wsW[64 * 136];   // 17408 B
  int tid = threadIdx.x, wv = tid >> 6, lane = tid & 63;
  int l15 = lane & 15, lhi = lane >> 4;
  int mbase = blockIdx.x * 256 + wv * 32;

  bf16x8 afr[2][4];
#pragma unroll
  for (int mt = 0; mt < 2; ++mt)
#pragma unroll
    for (int ks = 0; ks < 4; ++ks)
      afr[mt][ks] = *(const bf16x8*)(win + (size_t)(mbase + mt * 16 + l15) * 128 + ks * 32 + lhi * 8);

  int rbase[2][4];
#pragma unroll
  for (int mt = 0; mt < 2; ++mt)
#pragma unroll
    for (int j = 0; j < 4; ++j) {
      int r = mbase + mt * 16 + lhi * 4 + j;
      int widx = r / NT, n = r - widx * NT;
      rbase[mt][j] = widx * 392 + n;
    }

  bf16x8 pf[2];
#pragma unroll
  for (int u = 0; u < 2; ++u) pf[u] = *(const bf16x8*)(qkvT + u * 4096 + tid * 8);

  for (int ch = 0; ch < 6; ++ch) {
#pragma unroll
    for (int u = 0; u < 2; ++u) {
      int flat = u * 4096 + tid * 8;
      *(bf16x8*)(&wsW[(flat >> 7) * 136 + (flat & 127)]) = pf[u];
    }
    __syncthreads();
    if (ch < 5) {
#pragma unroll
      for (int u = 0; u < 2; ++u)
        pf[u] = *(const bf16x8*)(qkvT + (ch + 1) * 8192 + u * 4096 + tid * 8);
    }
    f32x4 acc[2][4] = {};
#pragma unroll
    for (int ks = 0; ks < 4; ++ks)
#pragma unroll
      for (int nt = 0; nt < 4; ++nt) {
        bf16x8 bfr = *(const bf16x8*)(&wsW[(nt * 16 + l15) * 136 + ks * 32 + lhi * 8]);
#pragma unroll
        for (int mt = 0; mt < 2; ++mt)
          acc[mt][nt] = MFMA(afr[mt][ks], bfr, acc[mt][nt]);
      }
#pragma unroll
    for (int nt = 0; nt < 4; ++nt) {
      int col = ch * 64 + nt * 16 + l15;
      int which = col >> 7, head = (col >> 5) & 3, hd = col & 31;
      unsigned short* outb = which == 0 ? q : (which == 1 ? k : v);
      float scale = which == 0 ? 0.17677669529663687f : 1.0f;
      float bias = qkv_b[col];
#pragma unroll
      for (int mt = 0; mt < 2; ++mt)
#pragma unroll
        for (int j = 0; j < 4; ++j) {
          float val = (acc[mt][nt][j] + bias) * scale;
          outb[(size_t)(rbase[mt][j] + head * 98) * 32 + hd] = f2bf(val);
        }
    }
    __syncthreads();
  }
}

// ---------------- K3: window attention, 512 thr, one 16-row tile per wave --
__global__ __launch_bounds__(512) void k3_attn(
    const unsigned short* __restrict__ q, const unsigned short* __restrict__ kk,
    const unsigned short* __restrict__ vv, const unsigned short* __restrict__ cmb,
    unsigned short* __restrict__ out) {
  __shared__ __align__(16) unsigned short Vt[32 * 140];    // 8960 B
  __shared__ __align__(16) unsigned short Pw[7][16 * 140]; // 31360 B
  int bid = blockIdx.x;
  int widx = bid >> 2, head = bid & 3;
  int wb = widx & 255;
  size_t base = (size_t)(widx * 4 + head) * NT * 32;
  int tid = threadIdx.x, wv = tid >> 6, lane = tid & 63;
  int l15 = lane & 15, lhi = lane >> 4;

  for (int idx = tid; idx < NT * 32; idx += 512) {
    int j = idx >> 5, d = idx & 31;
    Vt[d * 140 + j] = vv[base + idx];
  }
  for (int idx = tid; idx < 32 * 30; idx += 512) {
    int d = idx / 30, j = 98 + idx % 30;
    Vt[d * 140 + j] = 0;
  }
  __syncthreads();
  if (wv >= 7) return;           // no barriers after this point

  const unsigned short* cw = cmb + ((size_t)(head << 8) + wb) * NN;
  unsigned short* P = Pw[wv];
  int mb = wv * 16;

  bf16x8 afr = *(const bf16x8*)(q + base + (size_t)(mb + l15) * 32 + lhi * 8);
  f32x4 sfr[7];
#pragma unroll
  for (int nt = 0; nt < 7; ++nt) {
    bf16x8 bfr = *(const bf16x8*)(kk + base + (size_t)(nt * 16 + l15) * 32 + lhi * 8);
    f32x4 zz = {};
    sfr[nt] = MFMA(afr, bfr, zz);
  }
#pragma unroll
  for (int j = 0; j < 4; ++j) {
    int i = mb + lhi * 4 + j;
    int ic = i < 97 ? i : 97;
    float sv[7];
#pragma unroll
    for (int nt = 0; nt < 7; ++nt) {
      int colc = nt * 16 + l15;
      int jc = colc < 97 ? colc : 97;
      float s = fminf(fmaxf(sfr[nt][j], -1e4f), 1e4f);
      float bm = bf2f(cw[ic * NT + jc]);
      sv[nt] = (i < NT && colc < NT) ? (s + bm) : -1e30f;
    }
    float mx = sv[0];
#pragma unroll
    for (int nt = 1; nt < 7; ++nt) mx = fmaxf(mx, sv[nt]);
#pragma unroll
    for (int m2 = 1; m2 < 16; m2 <<= 1) mx = fmaxf(mx, __shfl_xor(mx, m2));
    float sum = 0.f, p[7];
#pragma unroll
    for (int nt = 0; nt < 7; ++nt) { p[nt] = __expf(sv[nt] - mx); sum += p[nt]; }
#pragma unroll
    for (int m2 = 1; m2 < 16; m2 <<= 1) sum += __shfl_xor(sum, m2);
    float inv = __builtin_amdgcn_rcpf(sum);
    int iloc = lhi * 4 + j;
#pragma unroll
    for (int nt = 0; nt < 7; ++nt)
      P[iloc * 140 + nt * 16 + l15] = f2bf(p[nt] * inv);
    P[iloc * 140 + 112 + l15] = 0;
  }
  WAVE_LDS_FENCE();

  f32x4 ofr[2] = {};
#pragma unroll
  for (int ks = 0; ks < 4; ++ks) {
    bf16x8 pafr = *(const bf16x8*)(P + l15 * 140 + ks * 32 + lhi * 8);
#pragma unroll
    for (int nt = 0; nt < 2; ++nt) {
      bf16x8 bfr = *(const bf16x8*)(Vt + (nt * 16 + l15) * 140 + ks * 32 + lhi * 8);
      ofr[nt] = MFMA(pafr, bfr, ofr[nt]);
    }
  }
#pragma unroll
  for (int nt = 0; nt < 2; ++nt)
#pragma unroll
    for (int j = 0; j < 4; ++j) {
      int n = mb + lhi * 4 + j;
      if (n < NT) {
        int d = nt * 16 + l15;
        out[(size_t)(widx * NT + n) * 128 + head * 32 + d] = f2bf(ofr[nt][j]);
      }
    }
}

// ---------------- K4: proj + reverse/unshift + residual + LN2 --------------
// 512 thr / 256 rows; projT staged ONCE per block
__global__ __launch_bounds__(512, 4) void k4_proj_ln(
    const unsigned short* __restrict__ ao, const unsigned short* __restrict__ projT,
    const float* __restrict__ proj_b, const float* __restrict__ x,
    const float* __restrict__ g2, const float* __restrict__ b2,
    unsigned short* __restrict__ z) {
  __shared__ __align__(16) unsigned short wsW[128 * 136];   // 34816 B
  int tid = threadIdx.x, wv = tid >> 6, lane = tid & 63;
  int l15 = lane & 15, lhi = lane >> 4;
  int mbase = blockIdx.x * 256 + wv * 32;

#pragma unroll
  for (int u = 0; u < 4; ++u) {
    int flat = u * 4096 + tid * 8;
    *(bf16x8*)(&wsW[(flat >> 7) * 136 + (flat & 127)]) = *(const bf16x8*)(projT + flat);
  }
  bf16x8 afr[2][4];
#pragma unroll
  for (int mt = 0; mt < 2; ++mt)
#pragma unroll
    for (int ks = 0; ks < 4; ++ks)
      afr[mt][ks] = *(const bf16x8*)(ao + (size_t)(mbase + mt * 16 + l15) * 128 + ks * 32 + lhi * 8);
  __syncthreads();

  f32x4 acc[2][8] = {};
#pragma unroll
  for (int ks = 0; ks < 4; ++ks)
#pragma unroll
    for (int nt = 0; nt < 8; ++nt) {
      bf16x8 bfr = *(const bf16x8*)(&wsW[(nt * 16 + l15) * 136 + ks * 32 + lhi * 8]);
#pragma unroll
      for (int mt = 0; mt < 2; ++mt)
        acc[mt][nt] = MFMA(afr[mt][ks], bfr, acc[mt][nt]);
    }

#pragma unroll
  for (int mt = 0; mt < 2; ++mt)
#pragma unroll
    for (int j = 0; j < 4; ++j) {
      int t = mbase + mt * 16 + lhi * 4 + j;
      int widx = t / NT, n = t - widx * NT;
      int bb = widx >> 8, wb = widx & 255;
      int dW = wb >> 6, hW = (wb >> 3) & 7, wW = wb & 7;
      int dr = n / 49, rem = n - dr * 49, hr = rem / 7, wr = rem - hr * 7;
      int d = (dW * 2 + dr + 1) & 7;
      int h = hW * 7 + hr + 3; if (h >= 56) h -= 56;
      int w = wW * 7 + wr + 3; if (w >= 56) w -= 56;
      size_t srow = ((size_t)(bb * 8 + d) * 56 + h) * 56 + w;
      float vals[8], s = 0.f, ss = 0.f;
#pragma unroll
      for (int nt = 0; nt < 8; ++nt) {
        int colc = nt * 16 + l15;
        float val = acc[mt][nt][j] + proj_b[colc] + x[srow * 128 + colc];
        vals[nt] = val; s += val; ss += val * val;
      }
#pragma unroll
      for (int m2 = 1; m2 < 16; m2 <<= 1) { s += __shfl_xor(s, m2); ss += __shfl_xor(ss, m2); }
      float mu = s * (1.f / 128.f);
      float var = ss * (1.f / 128.f) - mu * mu;
      float inv = __builtin_amdgcn_rsqf(var + 1e-5f);
#pragma unroll
      for (int nt = 0; nt < 8; ++nt) {
        int colc = nt * 16 + l15;
        z[srow * 128 + colc] = f2bf((vals[nt] - mu) * inv * g2[colc] + b2[colc]);
      }
    }
}

// ---------------- K5: MLP fc1 + GELU + fc2, 512 thr / 256 rows -------------
__global__ __launch_bounds__(512, 4) void k5_mlp(
    const unsigned short* __restrict__ z, const unsigned short* __restrict__ fc1T,
    const float* __restrict__ fc1_b, const unsigned short* __restrict__ fc2T,
    const float* __restrict__ fc2_b, float* __restrict__ out) {
  __shared__ __align__(16) unsigned short wsA[64 * 136];   // 17408 B
  __shared__ __align__(16) unsigned short wsB[128 * 72];   // 18432 B
  __shared__ __align__(16) unsigned short hl[8][32 * 70];  // 35840 B
  int tid = threadIdx.x, wv = tid >> 6, lane = tid & 63;
  int l15 = lane & 15, lhi = lane >> 4;
  int mbase = blockIdx.x * 256 + wv * 32;
  unsigned short* hw = hl[wv];

  bf16x8 afr[2][4];
#pragma unroll
  for (int mt = 0; mt < 2; ++mt)
#pragma unroll
    for (int ks = 0; ks < 4; ++ks)
      afr[mt][ks] = *(const bf16x8*)(z + (size_t)(mbase + mt * 16 + l15) * 128 + ks * 32 + lhi * 8);

  bf16x8 pfA[2], pfB[2];
#pragma unroll
  for (int u = 0; u < 2; ++u) pfA[u] = *(const bf16x8*)(fc1T + u * 4096 + tid * 8);
#pragma unroll
  for (int u = 0; u < 2; ++u) {
    int flat = u * 4096 + tid * 8;
    pfB[u] = *(const bf16x8*)(fc2T + (size_t)(flat >> 6) * 512 + (flat & 63));
  }

  f32x4 oacc[2][8] = {};
  for (int ch = 0; ch < 8; ++ch) {
#pragma unroll
    for (int u = 0; u < 2; ++u) {
      int flat = u * 4096 + tid * 8;
      *(bf16x8*)(&wsA[(flat >> 7) * 136 + (flat & 127)]) = pfA[u];
      *(bf16x8*)(&wsB[(flat >> 6) * 72 + (flat & 63)]) = pfB[u];
    }
    __syncthreads();
    if (ch < 7) {
#pragma unroll
      for (int u = 0; u < 2; ++u)
        pfA[u] = *(const bf16x8*)(fc1T + (ch + 1) * 8192 + u * 4096 + tid * 8);
#pragma unroll
      for (int u = 0; u < 2; ++u) {
        int flat = u * 4096 + tid * 8;
        pfB[u] = *(const bf16x8*)(fc2T + (size_t)(flat >> 6) * 512 + (ch + 1) * 64 + (flat & 63));
      }
    }
    // fc1: h[32 x 64] per wave
    f32x4 hacc[2][4] = {};
#pragma unroll
    for (int ks = 0; ks < 4; ++ks)
#pragma unroll
      for (int nt = 0; nt < 4; ++nt) {
        bf16x8 bfr = *(const bf16x8*)(&wsA[(nt * 16 + l15) * 136 + ks * 32 + lhi * 8]);
#pragma unroll
        for (int mt = 0; mt < 2; ++mt)
          hacc[mt][nt] = MFMA(afr[mt][ks], bfr, hacc[mt][nt]);
      }
#pragma unroll
    for (int mt = 0; mt < 2; ++mt)
#pragma unroll
      for (int nt = 0; nt < 4; ++nt)
#pragma unroll
        for (int j = 0; j < 4; ++j) {
          int r = mt * 16 + lhi * 4 + j;
          int hcol = ch * 64 + nt * 16 + l15;
          float hv = hacc[mt][nt][j] + fc1_b[hcol];
          // tanh-GELU via sigmoid + fast rcp (1 trans + 1 trans + ~5 VALU)
          float targ = hv * (1.5957691216f + 0.0713548162f * hv * hv);
          float gv = hv * __builtin_amdgcn_rcpf(1.0f + __expf(-targ));
          hw[r * 70 + nt * 16 + l15] = f2bf(gv);
        }
    WAVE_LDS_FENCE();
    // fc2: accumulate
#pragma unroll
    for (int ks = 0; ks < 2; ++ks) {
      bf16x8 a2[2];
#pragma unroll
      for (int mt = 0; mt < 2; ++mt)
        a2[mt] = *(const bf16x8*)(&hw[(mt * 16 + l15) * 70 + ks * 32 + lhi * 8]);
#pragma unroll
      for (int nt = 0; nt < 8; ++nt) {
        bf16x8 bfr = *(const bf16x8*)(&wsB[(nt * 16 + l15) * 72 + ks * 32 + lhi * 8]);
#pragma unroll
        for (int mt = 0; mt < 2; ++mt)
          oacc[mt][nt] = MFMA(a2[mt], bfr, oacc[mt][nt]);
      }
    }
    WAVE_LDS_FENCE();
    __syncthreads();
  }
#pragma unroll
  for (int mt = 0; mt < 2; ++mt)
#pragma unroll
    for (int nt = 0; nt < 8; ++nt)
#pragma unroll
      for (int j = 0; j < 4; ++j) {
        int r = mbase + mt * 16 + lhi * 4 + j;
        out[(size_t)r * 128 + nt * 16 + l15] = oacc[mt][nt][j] + fc2_b[nt * 16 + l15];
      }
}

// ---------------------------------------------------------------------------
extern "C" void kernel_launch(void* const* d_in, const int* in_sizes, int n_in,
                              void* d_out, int out_size, void* d_ws, size_t ws_size,
                              hipStream_t stream) {
  const float* x      = (const float*)d_in[0];
  const float* mask   = (const float*)d_in[1];
  const int*   rel    = (const int*)d_in[2];
  const float* n1g    = (const float*)d_in[3];
  const float* n1b    = (const float*)d_in[4];
  const float* qkv_w  = (const float*)d_in[5];
  const float* qkv_b  = (const float*)d_in[6];
  const float* rpb    = (const float*)d_in[7];
  const float* proj_w = (const float*)d_in[8];
  const float* proj_b = (const float*)d_in[9];
  const float* n2g    = (const float*)d_in[10];
  const float* n2b    = (const float*)d_in[11];
  const float* fc1_w  = (const float*)d_in[12];
  const float* fc1_b  = (const float*)d_in[13];
  const float* fc2_w  = (const float*)d_in[14];
  const float* fc2_b  = (const float*)d_in[15];
  float* out = (float*)d_out;

  char* ws = (char*)d_ws;
  const size_t SZ = (size_t)NTOK * 128 * 2;
  unsigned short* win   = (unsigned short*)(ws);
  unsigned short* qb    = (unsigned short*)(ws + SZ);
  unsigned short* kb    = (unsigned short*)(ws + 2 * SZ);
  unsigned short* vb    = (unsigned short*)(ws + 3 * SZ);
  unsigned short* qkvT  = (unsigned short*)(ws + 4 * SZ);
  unsigned short* projT = qkvT + 384 * 128;
  unsigned short* fc1T  = projT + 128 * 128;
  unsigned short* fc2T  = fc1T + 512 * 128;
  unsigned short* cmb   = fc2T + 128 * 512;     // 4*256*9604 bf16 = 19.7 MB
  unsigned short* ao = win;
  unsigned short* zb = qb;

  k0_prep<<<256, 256, 0, stream>>>(qkv_w, proj_w, fc1_w, fc2_w, qkvT, projT, fc1T, fc2T);
  k0b_cmb<<<(4 * 256 * NN + 255) / 256, 256, 0, stream>>>(rel, rpb, mask, cmb);
  k1_ln_part<<<NTOK / 4, 256, 0, stream>>>(x, n1g, n1b, win);
  k2_qkv<<<NTOK / 256, 512, 0, stream>>>(win, qkvT, qkv_b, qb, kb, vb);
  k3_attn<<<NWIN * 4, 512, 0, stream>>>(qb, kb, vb, cmb, ao);
  k4_proj_ln<<<NTOK / 256, 512, 0, stream>>>(ao, projT, proj_b, x, n2g, n2b, zb);
  k5_mlp<<<NTOK / 256, 512, 0, stream>>>(zb, fc1T, fc1_b, fc2T, fc2_b, out);
}

// Round 6
// 539.346 us; speedup vs baseline: 1.0645x; 1.0645x over previous
//
#include <hip/hip_runtime.h>
#include <hip/hip_bf16.h>

typedef __attribute__((ext_vector_type(8))) short bf16x8;
typedef __attribute__((ext_vector_type(4))) float f32x4;

#define MFMA(a,b,c) __builtin_amdgcn_mfma_f32_16x16x32_bf16((a),(b),(c),0,0,0)
#define WAVE_LDS_FENCE() do { asm volatile("s_waitcnt lgkmcnt(0)" ::: "memory"); \
                              __builtin_amdgcn_sched_barrier(0); } while (0)

static constexpr int NTOK = 8 * 8 * 56 * 56;   // 200704 tokens
static constexpr int NT   = 98;                // tokens per window
static constexpr int NWIN = 2048;              // total windows
static constexpr int NN   = NT * NT;           // 9604

__device__ __forceinline__ unsigned short f2bf(float f) {
  unsigned r;
  asm("v_cvt_pk_bf16_f32 %0, %1, %1" : "=v"(r) : "v"(f));
  return (unsigned short)r;
}
__device__ __forceinline__ unsigned f2bf2(float lo, float hi) {
  unsigned r;
  asm("v_cvt_pk_bf16_f32 %0, %1, %2" : "=v"(r) : "v"(lo), "v"(hi));
  return r;
}
__device__ __forceinline__ float bf2f(unsigned short s) {
  union { unsigned u; float f; } v; v.u = ((unsigned)s) << 16; return v.f;
}

// ---------------- K0: weight transpose + bf16 cast -------------------------
__global__ __launch_bounds__(256) void k0_prep(
    const float* __restrict__ qkv_w, const float* __restrict__ proj_w,
    const float* __restrict__ fc1_w, const float* __restrict__ fc2_w,
    unsigned short* __restrict__ qkvT, unsigned short* __restrict__ projT,
    unsigned short* __restrict__ fc1T, unsigned short* __restrict__ fc2T) {
  int idx = blockIdx.x * 256 + threadIdx.x;
  if (idx < 384 * 128) { int n = idx >> 7, k = idx & 127; qkvT[idx] = f2bf(qkv_w[k * 384 + n]); }
  if (idx < 128 * 128) { int n = idx >> 7, k = idx & 127; projT[idx] = f2bf(proj_w[k * 128 + n]); }
  if (idx < 512 * 128) { int n = idx >> 7, k = idx & 127; fc1T[idx] = f2bf(fc1_w[k * 512 + n]); }
  if (idx < 128 * 512) { int n = idx >> 9, k = idx & 511; fc2T[idx] = f2bf(fc2_w[k * 128 + n]); }
}

// ---------------- K0b: combined bias+mask table, bf16 ----------------------
__global__ __launch_bounds__(256) void k0b_cmb(
    const int* __restrict__ rel, const float* __restrict__ rpb,
    const float* __restrict__ mask, unsigned short* __restrict__ cmb) {
  int idx = blockIdx.x * 256 + threadIdx.x;
  if (idx >= 4 * 256 * NN) return;
  int h = idx / (256 * NN);
  int rem = idx - h * 256 * NN;
  int wb = rem / NN, r = rem - wb * NN;
  cmb[idx] = f2bf(rpb[rel[r] * 4 + h] + mask[(size_t)wb * NN + r]);
}

// ---------------- K1: LN1 + cyclic shift + window partition ----------------
__global__ __launch_bounds__(256) void k1_ln_part(
    const float* __restrict__ x, const float* __restrict__ g,
    const float* __restrict__ b, unsigned short* __restrict__ win) {
  int wv = threadIdx.x >> 6, lane = threadIdx.x & 63;
  int t = blockIdx.x * 4 + wv;
  int widx = t / NT, n = t - widx * NT;
  int bb = widx >> 8, wb = widx & 255;
  int dW = wb >> 6, hW = (wb >> 3) & 7, wW = wb & 7;
  int dr = n / 49, rem = n - dr * 49, hr = rem / 7, wr = rem - hr * 7;
  int ds = (dW * 2 + dr + 1) & 7;
  int hs = hW * 7 + hr + 3; if (hs >= 56) hs -= 56;
  int wsv = wW * 7 + wr + 3; if (wsv >= 56) wsv -= 56;
  size_t srow = ((size_t)(bb * 8 + ds) * 56 + hs) * 56 + wsv;
  const float2 v2 = *(const float2*)(x + srow * 128 + lane * 2);
  float s = v2.x + v2.y, ss = v2.x * v2.x + v2.y * v2.y;
#pragma unroll
  for (int m = 1; m < 64; m <<= 1) { s += __shfl_xor(s, m); ss += __shfl_xor(ss, m); }
  float mu = s * (1.f / 128.f);
  float var = ss * (1.f / 128.f) - mu * mu;
  float inv = __builtin_amdgcn_rsqf(var + 1e-5f);
  float g0 = g[lane * 2], g1 = g[lane * 2 + 1];
  float b0 = b[lane * 2], b1 = b[lane * 2 + 1];
  *(unsigned*)(win + (size_t)t * 128 + lane * 2) =
      f2bf2((v2.x - mu) * inv * g0 + b0, (v2.y - mu) * inv * g1 + b1);
}

// ---------------- K2: QKV GEMM, 256 thr / 128 rows, staged + prefetch ------
__global__ __launch_bounds__(256, 4) void k2_qkv(
    const unsigned short* __restrict__ win, const unsigned short* __restrict__ qkvT,
    const float* __restrict__ qkv_b,
    unsigned short* __restrict__ q, unsigned short* __restrict__ k,
    unsigned short* __restrict__ v) {
  __shared__ __align__(16) unsigned short wsW[64 * 136];   // 17408 B
  int tid = threadIdx.x, wv = tid >> 6, lane = tid & 63;
  int l15 = lane & 15, lhi = lane >> 4;
  int mbase = blockIdx.x * 128 + wv * 32;

  bf16x8 afr[2][4];
#pragma unroll
  for (int mt = 0; mt < 2; ++mt)
#pragma unroll
    for (int ks = 0; ks < 4; ++ks)
      afr[mt][ks] = *(const bf16x8*)(win + (size_t)(mbase + mt * 16 + l15) * 128 + ks * 32 + lhi * 8);

  int rbase[2][4];
#pragma unroll
  for (int mt = 0; mt < 2; ++mt)
#pragma unroll
    for (int j = 0; j < 4; ++j) {
      int r = mbase + mt * 16 + lhi * 4 + j;
      int widx = r / NT, n = r - widx * NT;
      rbase[mt][j] = widx * 392 + n;
    }

  bf16x8 pf[4];
#pragma unroll
  for (int u = 0; u < 4; ++u) pf[u] = *(const bf16x8*)(qkvT + u * 2048 + tid * 8);

  for (int ch = 0; ch < 6; ++ch) {
#pragma unroll
    for (int u = 0; u < 4; ++u) {
      int flat = u * 2048 + tid * 8;
      *(bf16x8*)(&wsW[(flat >> 7) * 136 + (flat & 127)]) = pf[u];
    }
    __syncthreads();
    if (ch < 5) {
#pragma unroll
      for (int u = 0; u < 4; ++u)
        pf[u] = *(const bf16x8*)(qkvT + (ch + 1) * 8192 + u * 2048 + tid * 8);
    }
    f32x4 acc[2][4] = {};
#pragma unroll
    for (int ks = 0; ks < 4; ++ks)
#pragma unroll
      for (int nt = 0; nt < 4; ++nt) {
        bf16x8 bfr = *(const bf16x8*)(&wsW[(nt * 16 + l15) * 136 + ks * 32 + lhi * 8]);
#pragma unroll
        for (int mt = 0; mt < 2; ++mt)
          acc[mt][nt] = MFMA(afr[mt][ks], bfr, acc[mt][nt]);
      }
#pragma unroll
    for (int nt = 0; nt < 4; ++nt) {
      int col = ch * 64 + nt * 16 + l15;
      int which = col >> 7, head = (col >> 5) & 3, hd = col & 31;
      unsigned short* outb = which == 0 ? q : (which == 1 ? k : v);
      float scale = which == 0 ? 0.17677669529663687f : 1.0f;
      float bias = qkv_b[col];
#pragma unroll
      for (int mt = 0; mt < 2; ++mt)
#pragma unroll
        for (int j = 0; j < 4; ++j) {
          float val = (acc[mt][nt][j] + bias) * scale;
          outb[(size_t)(rbase[mt][j] + head * 98) * 32 + hd] = f2bf(val);
        }
    }
    __syncthreads();
  }
}

// ---------------- K3: window attention, 512 thr, one 16-row tile per wave --
__global__ __launch_bounds__(512) void k3_attn(
    const unsigned short* __restrict__ q, const unsigned short* __restrict__ kk,
    const unsigned short* __restrict__ vv, const unsigned short* __restrict__ cmb,
    unsigned short* __restrict__ out) {
  __shared__ __align__(16) unsigned short Vt[32 * 140];    // 8960 B
  __shared__ __align__(16) unsigned short Pw[7][16 * 140]; // 31360 B
  int bid = blockIdx.x;
  int widx = bid >> 2, head = bid & 3;
  int wb = widx & 255;
  size_t base = (size_t)(widx * 4 + head) * NT * 32;
  int tid = threadIdx.x, wv = tid >> 6, lane = tid & 63;
  int l15 = lane & 15, lhi = lane >> 4;

  for (int idx = tid; idx < NT * 32; idx += 512) {
    int j = idx >> 5, d = idx & 31;
    Vt[d * 140 + j] = vv[base + idx];
  }
  for (int idx = tid; idx < 32 * 30; idx += 512) {
    int d = idx / 30, j = 98 + idx % 30;
    Vt[d * 140 + j] = 0;
  }
  __syncthreads();
  if (wv >= 7) return;           // no barriers after this point

  const unsigned short* cw = cmb + ((size_t)(head << 8) + wb) * NN;
  unsigned short* P = Pw[wv];
  int mb = wv * 16;

  bf16x8 afr = *(const bf16x8*)(q + base + (size_t)(mb + l15) * 32 + lhi * 8);
  f32x4 sfr[7];
#pragma unroll
  for (int nt = 0; nt < 7; ++nt) {
    bf16x8 bfr = *(const bf16x8*)(kk + base + (size_t)(nt * 16 + l15) * 32 + lhi * 8);
    f32x4 zz = {};
    sfr[nt] = MFMA(afr, bfr, zz);
  }
#pragma unroll
  for (int j = 0; j < 4; ++j) {
    int i = mb + lhi * 4 + j;
    int ic = i < 97 ? i : 97;
    float sv[7];
#pragma unroll
    for (int nt = 0; nt < 7; ++nt) {
      int colc = nt * 16 + l15;
      int jc = colc < 97 ? colc : 97;
      float s = fminf(fmaxf(sfr[nt][j], -1e4f), 1e4f);
      float bm = bf2f(cw[ic * NT + jc]);
      sv[nt] = (i < NT && colc < NT) ? (s + bm) : -1e30f;
    }
    float mx = sv[0];
#pragma unroll
    for (int nt = 1; nt < 7; ++nt) mx = fmaxf(mx, sv[nt]);
#pragma unroll
    for (int m2 = 1; m2 < 16; m2 <<= 1) mx = fmaxf(mx, __shfl_xor(mx, m2));
    float sum = 0.f, p[7];
#pragma unroll
    for (int nt = 0; nt < 7; ++nt) { p[nt] = __expf(sv[nt] - mx); sum += p[nt]; }
#pragma unroll
    for (int m2 = 1; m2 < 16; m2 <<= 1) sum += __shfl_xor(sum, m2);
    float inv = __builtin_amdgcn_rcpf(sum);
    int iloc = lhi * 4 + j;
#pragma unroll
    for (int nt = 0; nt < 7; ++nt)
      P[iloc * 140 + nt * 16 + l15] = f2bf(p[nt] * inv);
    P[iloc * 140 + 112 + l15] = 0;
  }
  WAVE_LDS_FENCE();

  f32x4 ofr[2] = {};
#pragma unroll
  for (int ks = 0; ks < 4; ++ks) {
    bf16x8 pafr = *(const bf16x8*)(P + l15 * 140 + ks * 32 + lhi * 8);
#pragma unroll
    for (int nt = 0; nt < 2; ++nt) {
      bf16x8 bfr = *(const bf16x8*)(Vt + (nt * 16 + l15) * 140 + ks * 32 + lhi * 8);
      ofr[nt] = MFMA(pafr, bfr, ofr[nt]);
    }
  }
#pragma unroll
  for (int nt = 0; nt < 2; ++nt)
#pragma unroll
    for (int j = 0; j < 4; ++j) {
      int n = mb + lhi * 4 + j;
      if (n < NT) {
        int d = nt * 16 + l15;
        out[(size_t)(widx * NT + n) * 128 + head * 32 + d] = f2bf(ofr[nt][j]);
      }
    }
}

// ---------------- K4: proj + reverse/unshift + residual + LN2 --------------
__global__ __launch_bounds__(256, 3) void k4_proj_ln(
    const unsigned short* __restrict__ ao, const unsigned short* __restrict__ projT,
    const float* __restrict__ proj_b, const float* __restrict__ x,
    const float* __restrict__ g2, const float* __restrict__ b2,
    unsigned short* __restrict__ z) {
  __shared__ __align__(16) unsigned short wsW[128 * 136];   // 34816 B
  int tid = threadIdx.x, wv = tid >> 6, lane = tid & 63;
  int l15 = lane & 15, lhi = lane >> 4;
  int mbase = blockIdx.x * 128 + wv * 32;

#pragma unroll
  for (int u = 0; u < 8; ++u) {
    int flat = u * 2048 + tid * 8;
    *(bf16x8*)(&wsW[(flat >> 7) * 136 + (flat & 127)]) = *(const bf16x8*)(projT + flat);
  }
  bf16x8 afr[2][4];
#pragma unroll
  for (int mt = 0; mt < 2; ++mt)
#pragma unroll
    for (int ks = 0; ks < 4; ++ks)
      afr[mt][ks] = *(const bf16x8*)(ao + (size_t)(mbase + mt * 16 + l15) * 128 + ks * 32 + lhi * 8);
  __syncthreads();

  f32x4 acc[2][8] = {};
#pragma unroll
  for (int ks = 0; ks < 4; ++ks)
#pragma unroll
    for (int nt = 0; nt < 8; ++nt) {
      bf16x8 bfr = *(const bf16x8*)(&wsW[(nt * 16 + l15) * 136 + ks * 32 + lhi * 8]);
#pragma unroll
      for (int mt = 0; mt < 2; ++mt)
        acc[mt][nt] = MFMA(afr[mt][ks], bfr, acc[mt][nt]);
    }

#pragma unroll
  for (int mt = 0; mt < 2; ++mt)
#pragma unroll
    for (int j = 0; j < 4; ++j) {
      int t = mbase + mt * 16 + lhi * 4 + j;
      int widx = t / NT, n = t - widx * NT;
      int bb = widx >> 8, wb = widx & 255;
      int dW = wb >> 6, hW = (wb >> 3) & 7, wW = wb & 7;
      int dr = n / 49, rem = n - dr * 49, hr = rem / 7, wr = rem - hr * 7;
      int d = (dW * 2 + dr + 1) & 7;
      int h = hW * 7 + hr + 3; if (h >= 56) h -= 56;
      int w = wW * 7 + wr + 3; if (w >= 56) w -= 56;
      size_t srow = ((size_t)(bb * 8 + d) * 56 + h) * 56 + w;
      float vals[8], s = 0.f, ss = 0.f;
#pragma unroll
      for (int nt = 0; nt < 8; ++nt) {
        int colc = nt * 16 + l15;
        float val = acc[mt][nt][j] + proj_b[colc] + x[srow * 128 + colc];
        vals[nt] = val; s += val; ss += val * val;
      }
#pragma unroll
      for (int m2 = 1; m2 < 16; m2 <<= 1) { s += __shfl_xor(s, m2); ss += __shfl_xor(ss, m2); }
      float mu = s * (1.f / 128.f);
      float var = ss * (1.f / 128.f) - mu * mu;
      float inv = __builtin_amdgcn_rsqf(var + 1e-5f);
#pragma unroll
      for (int nt = 0; nt < 8; ++nt) {
        int colc = nt * 16 + l15;
        z[srow * 128 + colc] = f2bf((vals[nt] - mu) * inv * g2[colc] + b2[colc]);
      }
    }
}

// ---------------- K5: MLP fc1 + GELU + fc2, 256 thr, 3 blocks/CU -----------
// LDS trimmed to 52224 B (wsA 132 / wsB 68 / hl 70 pitches) -> 3 blocks/CU
__global__ __launch_bounds__(256, 3) void k5_mlp(
    const unsigned short* __restrict__ z, const unsigned short* __restrict__ fc1T,
    const float* __restrict__ fc1_b, const unsigned short* __restrict__ fc2T,
    const float* __restrict__ fc2_b, float* __restrict__ out) {
  __shared__ __align__(16) unsigned short wsA[64 * 132];   // 16896 B
  __shared__ __align__(16) unsigned short wsB[128 * 68];   // 17408 B
  __shared__ __align__(16) unsigned short hl[4][32 * 70];  // 17920 B
  int tid = threadIdx.x, wv = tid >> 6, lane = tid & 63;
  int l15 = lane & 15, lhi = lane >> 4;
  int mbase = blockIdx.x * 128 + wv * 32;
  unsigned short* hw = hl[wv];

  bf16x8 afr[2][4];
#pragma unroll
  for (int mt = 0; mt < 2; ++mt)
#pragma unroll
    for (int ks = 0; ks < 4; ++ks)
      afr[mt][ks] = *(const bf16x8*)(z + (size_t)(mbase + mt * 16 + l15) * 128 + ks * 32 + lhi * 8);

  bf16x8 pfA[4], pfB[4];
#pragma unroll
  for (int u = 0; u < 4; ++u) pfA[u] = *(const bf16x8*)(fc1T + u * 2048 + tid * 8);
#pragma unroll
  for (int u = 0; u < 4; ++u) {
    int flat = u * 2048 + tid * 8;
    pfB[u] = *(const bf16x8*)(fc2T + (size_t)(flat >> 6) * 512 + (flat & 63));
  }

  f32x4 oacc[2][8] = {};
  for (int ch = 0; ch < 8; ++ch) {
#pragma unroll
    for (int u = 0; u < 4; ++u) {
      int flat = u * 2048 + tid * 8;
      *(bf16x8*)(&wsA[(flat >> 7) * 132 + (flat & 127)]) = pfA[u];
      *(bf16x8*)(&wsB[(flat >> 6) * 68 + (flat & 63)]) = pfB[u];
    }
    __syncthreads();
    if (ch < 7) {
#pragma unroll
      for (int u = 0; u < 4; ++u)
        pfA[u] = *(const bf16x8*)(fc1T + (ch + 1) * 8192 + u * 2048 + tid * 8);
#pragma unroll
      for (int u = 0; u < 4; ++u) {
        int flat = u * 2048 + tid * 8;
        pfB[u] = *(const bf16x8*)(fc2T + (size_t)(flat >> 6) * 512 + (ch + 1) * 64 + (flat & 63));
      }
    }
    // fc1: h[32 x 64] per wave
    f32x4 hacc[2][4] = {};
#pragma unroll
    for (int ks = 0; ks < 4; ++ks)
#pragma unroll
      for (int nt = 0; nt < 4; ++nt) {
        bf16x8 bfr = *(const bf16x8*)(&wsA[(nt * 16 + l15) * 132 + ks * 32 + lhi * 8]);
#pragma unroll
        for (int mt = 0; mt < 2; ++mt)
          hacc[mt][nt] = MFMA(afr[mt][ks], bfr, hacc[mt][nt]);
      }
#pragma unroll
    for (int mt = 0; mt < 2; ++mt)
#pragma unroll
      for (int nt = 0; nt < 4; ++nt)
#pragma unroll
        for (int j = 0; j < 4; ++j) {
          int r = mt * 16 + lhi * 4 + j;
          int hcol = ch * 64 + nt * 16 + l15;
          float hv = hacc[mt][nt][j] + fc1_b[hcol];
          float targ = hv * (1.5957691216f + 0.0713548162f * hv * hv);
          float gv = hv * __builtin_amdgcn_rcpf(1.0f + __expf(-targ));
          hw[r * 70 + nt * 16 + l15] = f2bf(gv);
        }
    WAVE_LDS_FENCE();
    // fc2: accumulate
#pragma unroll
    for (int ks = 0; ks < 2; ++ks) {
      bf16x8 a2[2];
#pragma unroll
      for (int mt = 0; mt < 2; ++mt)
        a2[mt] = *(const bf16x8*)(&hw[(mt * 16 + l15) * 70 + ks * 32 + lhi * 8]);
#pragma unroll
      for (int nt = 0; nt < 8; ++nt) {
        bf16x8 bfr = *(const bf16x8*)(&wsB[(nt * 16 + l15) * 68 + ks * 32 + lhi * 8]);
#pragma unroll
        for (int mt = 0; mt < 2; ++mt)
          oacc[mt][nt] = MFMA(a2[mt], bfr, oacc[mt][nt]);
      }
    }
    WAVE_LDS_FENCE();
    __syncthreads();
  }
#pragma unroll
  for (int mt = 0; mt < 2; ++mt)
#pragma unroll
    for (int nt = 0; nt < 8; ++nt)
#pragma unroll
      for (int j = 0; j < 4; ++j) {
        int r = mbase + mt * 16 + lhi * 4 + j;
        out[(size_t)r * 128 + nt * 16 + l15] = oacc[mt][nt][j] + fc2_b[nt * 16 + l15];
      }
}

// ---------------------------------------------------------------------------
extern "C" void kernel_launch(void* const* d_in, const int* in_sizes, int n_in,
                              void* d_out, int out_size, void* d_ws, size_t ws_size,
                              hipStream_t stream) {
  const float* x      = (const float*)d_in[0];
  const float* mask   = (const float*)d_in[1];
  const int*   rel    = (const int*)d_in[2];
  const float* n1g    = (const float*)d_in[3];
  const float* n1b    = (const float*)d_in[4];
  const float* qkv_w  = (const float*)d_in[5];
  const float* qkv_b  = (const float*)d_in[6];
  const float* rpb    = (const float*)d_in[7];
  const float* proj_w = (const float*)d_in[8];
  const float* proj_b = (const float*)d_in[9];
  const float* n2g    = (const float*)d_in[10];
  const float* n2b    = (const float*)d_in[11];
  const float* fc1_w  = (const float*)d_in[12];
  const float* fc1_b  = (const float*)d_in[13];
  const float* fc2_w  = (const float*)d_in[14];
  const float* fc2_b  = (const float*)d_in[15];
  float* out = (float*)d_out;

  char* ws = (char*)d_ws;
  const size_t SZ = (size_t)NTOK * 128 * 2;
  unsigned short* win   = (unsigned short*)(ws);
  unsigned short* qb    = (unsigned short*)(ws + SZ);
  unsigned short* kb    = (unsigned short*)(ws + 2 * SZ);
  unsigned short* vb    = (unsigned short*)(ws + 3 * SZ);
  unsigned short* qkvT  = (unsigned short*)(ws + 4 * SZ);
  unsigned short* projT = qkvT + 384 * 128;
  unsigned short* fc1T  = projT + 128 * 128;
  unsigned short* fc2T  = fc1T + 512 * 128;
  unsigned short* cmb   = fc2T + 128 * 512;     // 4*256*9604 bf16 = 19.7 MB
  unsigned short* ao = win;
  unsigned short* zb = qb;

  k0_prep<<<256, 256, 0, stream>>>(qkv_w, proj_w, fc1_w, fc2_w, qkvT, projT, fc1T, fc2T);
  k0b_cmb<<<(4 * 256 * NN + 255) / 256, 256, 0, stream>>>(rel, rpb, mask, cmb);
  k1_ln_part<<<NTOK / 4, 256, 0, stream>>>(x, n1g, n1b, win);
  k2_qkv<<<NTOK / 128, 256, 0, stream>>>(win, qkvT, qkv_b, qb, kb, vb);
  k3_attn<<<NWIN * 4, 512, 0, stream>>>(qb, kb, vb, cmb, ao);
  k4_proj_ln<<<NTOK / 128, 256, 0, stream>>>(ao, projT, proj_b, x, n2g, n2b, zb);
  k5_mlp<<<NTOK / 128, 256, 0, stream>>>(zb, fc1T, fc1_b, fc2T, fc2_b, out);
}

// Round 7
// 436.752 us; speedup vs baseline: 1.3146x; 1.2349x over previous
//
#include <hip/hip_runtime.h>
#include <hip/hip_bf16.h>

typedef __attribute__((ext_vector_type(8))) short bf16x8;
typedef __attribute__((ext_vector_type(4))) float f32x4;

#define MFMA(a,b,c) __builtin_amdgcn_mfma_f32_16x16x32_bf16((a),(b),(c),0,0,0)
#define WAVE_LDS_FENCE() do { asm volatile("s_waitcnt lgkmcnt(0)" ::: "memory"); \
                              __builtin_amdgcn_sched_barrier(0); } while (0)

static constexpr int NTOK = 8 * 8 * 56 * 56;   // 200704 tokens
static constexpr int NT   = 98;                // tokens per window
static constexpr int NWIN = 2048;              // total windows
static constexpr int NN   = NT * NT;           // 9604

__device__ __forceinline__ unsigned short f2bf(float f) {
  unsigned r;
  asm("v_cvt_pk_bf16_f32 %0, %1, %1" : "=v"(r) : "v"(f));
  return (unsigned short)r;
}
__device__ __forceinline__ unsigned f2bf2(float lo, float hi) {
  unsigned r;
  asm("v_cvt_pk_bf16_f32 %0, %1, %2" : "=v"(r) : "v"(lo), "v"(hi));
  return r;
}
__device__ __forceinline__ float bf2f(unsigned short s) {
  union { unsigned u; float f; } v; v.u = ((unsigned)s) << 16; return v.f;
}
union U8 { unsigned u[4]; bf16x8 v; };

// ---------------- K0: weight transpose + bf16 cast + LN1 fold --------------
// qkvT[col][k] = bf16( qkv_w[k][col] * n1g[k] );  qbb[col] = qkv_b + n1b @ W
__global__ __launch_bounds__(256) void k0_prep(
    const float* __restrict__ qkv_w, const float* __restrict__ proj_w,
    const float* __restrict__ fc1_w, const float* __restrict__ fc2_w,
    const float* __restrict__ n1g, const float* __restrict__ n1b,
    const float* __restrict__ qkv_b,
    unsigned short* __restrict__ qkvT, unsigned short* __restrict__ projT,
    unsigned short* __restrict__ fc1T, unsigned short* __restrict__ fc2T,
    float* __restrict__ qbb) {
  int idx = blockIdx.x * 256 + threadIdx.x;
  if (idx < 384 * 128) { int n = idx >> 7, k = idx & 127; qkvT[idx] = f2bf(qkv_w[k * 384 + n] * n1g[k]); }
  if (idx < 128 * 128) { int n = idx >> 7, k = idx & 127; projT[idx] = f2bf(proj_w[k * 128 + n]); }
  if (idx < 512 * 128) { int n = idx >> 7, k = idx & 127; fc1T[idx] = f2bf(fc1_w[k * 512 + n]); }
  if (idx < 128 * 512) { int n = idx >> 9, k = idx & 511; fc2T[idx] = f2bf(fc2_w[k * 128 + n]); }
  if (idx < 384) {
    float acc = qkv_b[idx];
    for (int k = 0; k < 128; ++k) acc += n1b[k] * qkv_w[k * 384 + idx];
    qbb[idx] = acc;
  }
}

// ---------------- K0b: combined bias+mask table, bf16 ----------------------
__global__ __launch_bounds__(256) void k0b_cmb(
    const int* __restrict__ rel, const float* __restrict__ rpb,
    const float* __restrict__ mask, unsigned short* __restrict__ cmb) {
  int idx = blockIdx.x * 256 + threadIdx.x;
  if (idx >= 4 * 256 * NN) return;
  int h = idx / (256 * NN);
  int rem = idx - h * 256 * NN;
  int wb = rem / NN, r = rem - wb * NN;
  cmb[idx] = f2bf(rpb[rel[r] * 4 + h] + mask[(size_t)wb * NN + r]);
}

// ---------------- K2: fused LN1 + shift/partition + QKV GEMM ---------------
// reads x directly; LN in-register (row stats via shfl over lhi group);
// g1/b1 folded into qkvT/qbb by k0. 256 thr / 128 rows; weights LDS-staged.
__global__ __launch_bounds__(256, 2) void k2_qkv(
    const float* __restrict__ x, const unsigned short* __restrict__ qkvT,
    const float* __restrict__ qbb,
    unsigned short* __restrict__ q, unsigned short* __restrict__ k,
    unsigned short* __restrict__ v) {
  __shared__ __align__(16) unsigned short wsW[64 * 136];   // 17408 B
  int tid = threadIdx.x, wv = tid >> 6, lane = tid & 63;
  int l15 = lane & 15, lhi = lane >> 4;
  int mbase = blockIdx.x * 128 + wv * 32;

  bf16x8 afr[2][4];
#pragma unroll
  for (int mt = 0; mt < 2; ++mt) {
    int row = mbase + mt * 16 + l15;
    int widx = row / NT, n = row - widx * NT;
    int bb = widx >> 8, wb = widx & 255;
    int dW = wb >> 6, hW = (wb >> 3) & 7, wW = wb & 7;
    int dr = n / 49, rem = n - dr * 49, hr = rem / 7, wr = rem - hr * 7;
    int dsh = (dW * 2 + dr + 1) & 7;
    int hs = hW * 7 + hr + 3; if (hs >= 56) hs -= 56;
    int wsv = wW * 7 + wr + 3; if (wsv >= 56) wsv -= 56;
    size_t srow = ((size_t)(bb * 8 + dsh) * 56 + hs) * 56 + wsv;
    const float* xr = x + srow * 128 + lhi * 8;
    float xv[4][8];
    float s = 0.f, ss = 0.f;
#pragma unroll
    for (int ks = 0; ks < 4; ++ks) {
      float4 lo = *(const float4*)(xr + ks * 32);
      float4 hi = *(const float4*)(xr + ks * 32 + 4);
      xv[ks][0] = lo.x; xv[ks][1] = lo.y; xv[ks][2] = lo.z; xv[ks][3] = lo.w;
      xv[ks][4] = hi.x; xv[ks][5] = hi.y; xv[ks][6] = hi.z; xv[ks][7] = hi.w;
#pragma unroll
      for (int e = 0; e < 8; ++e) { s += xv[ks][e]; ss += xv[ks][e] * xv[ks][e]; }
    }
    s += __shfl_xor(s, 16);  ss += __shfl_xor(ss, 16);
    s += __shfl_xor(s, 32);  ss += __shfl_xor(ss, 32);
    float mu = s * (1.f / 128.f);
    float var = ss * (1.f / 128.f) - mu * mu;
    float inv = __builtin_amdgcn_rsqf(var + 1e-5f);
#pragma unroll
    for (int ks = 0; ks < 4; ++ks) {
      U8 t;
#pragma unroll
      for (int p = 0; p < 4; ++p)
        t.u[p] = f2bf2((xv[ks][2 * p] - mu) * inv, (xv[ks][2 * p + 1] - mu) * inv);
      afr[mt][ks] = t.v;
    }
  }

  int rbase[2][4];
#pragma unroll
  for (int mt = 0; mt < 2; ++mt)
#pragma unroll
    for (int j = 0; j < 4; ++j) {
      int r = mbase + mt * 16 + lhi * 4 + j;
      int widx = r / NT, n = r - widx * NT;
      rbase[mt][j] = widx * 392 + n;
    }

  bf16x8 pf[4];
#pragma unroll
  for (int u = 0; u < 4; ++u) pf[u] = *(const bf16x8*)(qkvT + u * 2048 + tid * 8);

  for (int ch = 0; ch < 6; ++ch) {
#pragma unroll
    for (int u = 0; u < 4; ++u) {
      int flat = u * 2048 + tid * 8;
      *(bf16x8*)(&wsW[(flat >> 7) * 136 + (flat & 127)]) = pf[u];
    }
    __syncthreads();
    if (ch < 5) {
#pragma unroll
      for (int u = 0; u < 4; ++u)
        pf[u] = *(const bf16x8*)(qkvT + (ch + 1) * 8192 + u * 2048 + tid * 8);
    }
    f32x4 acc[2][4] = {};
#pragma unroll
    for (int ks = 0; ks < 4; ++ks)
#pragma unroll
      for (int nt = 0; nt < 4; ++nt) {
        bf16x8 bfr = *(const bf16x8*)(&wsW[(nt * 16 + l15) * 136 + ks * 32 + lhi * 8]);
#pragma unroll
        for (int mt = 0; mt < 2; ++mt)
          acc[mt][nt] = MFMA(afr[mt][ks], bfr, acc[mt][nt]);
      }
#pragma unroll
    for (int nt = 0; nt < 4; ++nt) {
      int col = ch * 64 + nt * 16 + l15;
      int which = col >> 7, head = (col >> 5) & 3, hd = col & 31;
      unsigned short* outb = which == 0 ? q : (which == 1 ? k : v);
      float scale = which == 0 ? 0.17677669529663687f : 1.0f;
      float bias = qbb[col];
#pragma unroll
      for (int mt = 0; mt < 2; ++mt)
#pragma unroll
        for (int j = 0; j < 4; ++j) {
          float val = (acc[mt][nt][j] + bias) * scale;
          outb[(size_t)(rbase[mt][j] + head * 98) * 32 + hd] = f2bf(val);
        }
    }
    __syncthreads();
  }
}

// ---------------- K3: window attention, 512 thr, one 16-row tile per wave --
__global__ __launch_bounds__(512) void k3_attn(
    const unsigned short* __restrict__ q, const unsigned short* __restrict__ kk,
    const unsigned short* __restrict__ vv, const unsigned short* __restrict__ cmb,
    unsigned short* __restrict__ out) {
  __shared__ __align__(16) unsigned short Vt[32 * 140];    // 8960 B
  __shared__ __align__(16) unsigned short Pw[7][16 * 140]; // 31360 B
  int bid = blockIdx.x;
  int widx = bid >> 2, head = bid & 3;
  int wb = widx & 255;
  size_t base = (size_t)(widx * 4 + head) * NT * 32;
  int tid = threadIdx.x, wv = tid >> 6, lane = tid & 63;
  int l15 = lane & 15, lhi = lane >> 4;

  for (int idx = tid; idx < NT * 32; idx += 512) {
    int j = idx >> 5, d = idx & 31;
    Vt[d * 140 + j] = vv[base + idx];
  }
  for (int idx = tid; idx < 32 * 30; idx += 512) {
    int d = idx / 30, j = 98 + idx % 30;
    Vt[d * 140 + j] = 0;
  }
  __syncthreads();
  if (wv >= 7) return;           // no barriers after this point

  const unsigned short* cw = cmb + ((size_t)(head << 8) + wb) * NN;
  unsigned short* P = Pw[wv];
  int mb = wv * 16;

  bf16x8 afr = *(const bf16x8*)(q + base + (size_t)(mb + l15) * 32 + lhi * 8);
  f32x4 sfr[7];
#pragma unroll
  for (int nt = 0; nt < 7; ++nt) {
    bf16x8 bfr = *(const bf16x8*)(kk + base + (size_t)(nt * 16 + l15) * 32 + lhi * 8);
    f32x4 zz = {};
    sfr[nt] = MFMA(afr, bfr, zz);
  }
#pragma unroll
  for (int j = 0; j < 4; ++j) {
    int i = mb + lhi * 4 + j;
    int ic = i < 97 ? i : 97;
    float sv[7];
#pragma unroll
    for (int nt = 0; nt < 7; ++nt) {
      int colc = nt * 16 + l15;
      int jc = colc < 97 ? colc : 97;
      float s = fminf(fmaxf(sfr[nt][j], -1e4f), 1e4f);
      float bm = bf2f(cw[ic * NT + jc]);
      sv[nt] = (i < NT && colc < NT) ? (s + bm) : -1e30f;
    }
    float mx = sv[0];
#pragma unroll
    for (int nt = 1; nt < 7; ++nt) mx = fmaxf(mx, sv[nt]);
#pragma unroll
    for (int m2 = 1; m2 < 16; m2 <<= 1) mx = fmaxf(mx, __shfl_xor(mx, m2));
    float sum = 0.f, p[7];
#pragma unroll
    for (int nt = 0; nt < 7; ++nt) { p[nt] = __expf(sv[nt] - mx); sum += p[nt]; }
#pragma unroll
    for (int m2 = 1; m2 < 16; m2 <<= 1) sum += __shfl_xor(sum, m2);
    float inv = __builtin_amdgcn_rcpf(sum);
    int iloc = lhi * 4 + j;
#pragma unroll
    for (int nt = 0; nt < 7; ++nt)
      P[iloc * 140 + nt * 16 + l15] = f2bf(p[nt] * inv);
    P[iloc * 140 + 112 + l15] = 0;
  }
  WAVE_LDS_FENCE();

  f32x4 ofr[2] = {};
#pragma unroll
  for (int ks = 0; ks < 4; ++ks) {
    bf16x8 pafr = *(const bf16x8*)(P + l15 * 140 + ks * 32 + lhi * 8);
#pragma unroll
    for (int nt = 0; nt < 2; ++nt) {
      bf16x8 bfr = *(const bf16x8*)(Vt + (nt * 16 + l15) * 140 + ks * 32 + lhi * 8);
      ofr[nt] = MFMA(pafr, bfr, ofr[nt]);
    }
  }
#pragma unroll
  for (int nt = 0; nt < 2; ++nt)
#pragma unroll
    for (int j = 0; j < 4; ++j) {
      int n = mb + lhi * 4 + j;
      if (n < NT) {
        int d = nt * 16 + l15;
        out[(size_t)(widx * NT + n) * 128 + head * 32 + d] = f2bf(ofr[nt][j]);
      }
    }
}

// ---------------- K4: proj + reverse/unshift + residual + LN2 --------------
__global__ __launch_bounds__(256, 3) void k4_proj_ln(
    const unsigned short* __restrict__ ao, const unsigned short* __restrict__ projT,
    const float* __restrict__ proj_b, const float* __restrict__ x,
    const float* __restrict__ g2, const float* __restrict__ b2,
    unsigned short* __restrict__ z) {
  __shared__ __align__(16) unsigned short wsW[128 * 136];   // 34816 B
  int tid = threadIdx.x, wv = tid >> 6, lane = tid & 63;
  int l15 = lane & 15, lhi = lane >> 4;
  int mbase = blockIdx.x * 128 + wv * 32;

#pragma unroll
  for (int u = 0; u < 8; ++u) {
    int flat = u * 2048 + tid * 8;
    *(bf16x8*)(&wsW[(flat >> 7) * 136 + (flat & 127)]) = *(const bf16x8*)(projT + flat);
  }
  bf16x8 afr[2][4];
#pragma unroll
  for (int mt = 0; mt < 2; ++mt)
#pragma unroll
    for (int ks = 0; ks < 4; ++ks)
      afr[mt][ks] = *(const bf16x8*)(ao + (size_t)(mbase + mt * 16 + l15) * 128 + ks * 32 + lhi * 8);
  __syncthreads();

  f32x4 acc[2][8] = {};
#pragma unroll
  for (int ks = 0; ks < 4; ++ks)
#pragma unroll
    for (int nt = 0; nt < 8; ++nt) {
      bf16x8 bfr = *(const bf16x8*)(&wsW[(nt * 16 + l15) * 136 + ks * 32 + lhi * 8]);
#pragma unroll
      for (int mt = 0; mt < 2; ++mt)
        acc[mt][nt] = MFMA(afr[mt][ks], bfr, acc[mt][nt]);
    }

#pragma unroll
  for (int mt = 0; mt < 2; ++mt)
#pragma unroll
    for (int j = 0; j < 4; ++j) {
      int t = mbase + mt * 16 + lhi * 4 + j;
      int widx = t / NT, n = t - widx * NT;
      int bb = widx >> 8, wb = widx & 255;
      int dW = wb >> 6, hW = (wb >> 3) & 7, wW = wb & 7;
      int dr = n / 49, rem = n - dr * 49, hr = rem / 7, wr = rem - hr * 7;
      int d = (dW * 2 + dr + 1) & 7;
      int h = hW * 7 + hr + 3; if (h >= 56) h -= 56;
      int w = wW * 7 + wr + 3; if (w >= 56) w -= 56;
      size_t srow = ((size_t)(bb * 8 + d) * 56 + h) * 56 + w;
      float vals[8], s = 0.f, ss = 0.f;
#pragma unroll
      for (int nt = 0; nt < 8; ++nt) {
        int colc = nt * 16 + l15;
        float val = acc[mt][nt][j] + proj_b[colc] + x[srow * 128 + colc];
        vals[nt] = val; s += val; ss += val * val;
      }
#pragma unroll
      for (int m2 = 1; m2 < 16; m2 <<= 1) { s += __shfl_xor(s, m2); ss += __shfl_xor(ss, m2); }
      float mu = s * (1.f / 128.f);
      float var = ss * (1.f / 128.f) - mu * mu;
      float inv = __builtin_amdgcn_rsqf(var + 1e-5f);
#pragma unroll
      for (int nt = 0; nt < 8; ++nt) {
        int colc = nt * 16 + l15;
        z[srow * 128 + colc] = f2bf((vals[nt] - mu) * inv * g2[colc] + b2[colc]);
      }
    }
}

// ---------------- K5: MLP fc1 + GELU + fc2 ---------------------------------
// (256,2): no VGPR squeeze (R5/R6 lesson); LDS 52224 B -> 3 blocks/CU;
// pitches 132/68/70 conflict-light.
__global__ __launch_bounds__(256, 2) void k5_mlp(
    const unsigned short* __restrict__ z, const unsigned short* __restrict__ fc1T,
    const float* __restrict__ fc1_b, const unsigned short* __restrict__ fc2T,
    const float* __restrict__ fc2_b, float* __restrict__ out) {
  __shared__ __align__(16) unsigned short wsA[64 * 132];   // 16896 B
  __shared__ __align__(16) unsigned short wsB[128 * 68];   // 17408 B
  __shared__ __align__(16) unsigned short hl[4][32 * 70];  // 17920 B
  int tid = threadIdx.x, wv = tid >> 6, lane = tid & 63;
  int l15 = lane & 15, lhi = lane >> 4;
  int mbase = blockIdx.x * 128 + wv * 32;
  unsigned short* hw = hl[wv];

  bf16x8 afr[2][4];
#pragma unroll
  for (int mt = 0; mt < 2; ++mt)
#pragma unroll
    for (int ks = 0; ks < 4; ++ks)
      afr[mt][ks] = *(const bf16x8*)(z + (size_t)(mbase + mt * 16 + l15) * 128 + ks * 32 + lhi * 8);

  bf16x8 pfA[4], pfB[4];
#pragma unroll
  for (int u = 0; u < 4; ++u) pfA[u] = *(const bf16x8*)(fc1T + u * 2048 + tid * 8);
#pragma unroll
  for (int u = 0; u < 4; ++u) {
    int flat = u * 2048 + tid * 8;
    pfB[u] = *(const bf16x8*)(fc2T + (size_t)(flat >> 6) * 512 + (flat & 63));
  }

  f32x4 oacc[2][8] = {};
  for (int ch = 0; ch < 8; ++ch) {
#pragma unroll
    for (int u = 0; u < 4; ++u) {
      int flat = u * 2048 + tid * 8;
      *(bf16x8*)(&wsA[(flat >> 7) * 132 + (flat & 127)]) = pfA[u];
      *(bf16x8*)(&wsB[(flat >> 6) * 68 + (flat & 63)]) = pfB[u];
    }
    __syncthreads();
    if (ch < 7) {
#pragma unroll
      for (int u = 0; u < 4; ++u)
        pfA[u] = *(const bf16x8*)(fc1T + (ch + 1) * 8192 + u * 2048 + tid * 8);
#pragma unroll
      for (int u = 0; u < 4; ++u) {
        int flat = u * 2048 + tid * 8;
        pfB[u] = *(const bf16x8*)(fc2T + (size_t)(flat >> 6) * 512 + (ch + 1) * 64 + (flat & 63));
      }
    }
    // fc1: h[32 x 64] per wave
    f32x4 hacc[2][4] = {};
#pragma unroll
    for (int ks = 0; ks < 4; ++ks)
#pragma unroll
      for (int nt = 0; nt < 4; ++nt) {
        bf16x8 bfr = *(const bf16x8*)(&wsA[(nt * 16 + l15) * 132 + ks * 32 + lhi * 8]);
#pragma unroll
        for (int mt = 0; mt < 2; ++mt)
          hacc[mt][nt] = MFMA(afr[mt][ks], bfr, hacc[mt][nt]);
      }
#pragma unroll
    for (int mt = 0; mt < 2; ++mt)
#pragma unroll
      for (int nt = 0; nt < 4; ++nt)
#pragma unroll
        for (int j = 0; j < 4; ++j) {
          int r = mt * 16 + lhi * 4 + j;
          int hcol = ch * 64 + nt * 16 + l15;
          float hv = hacc[mt][nt][j] + fc1_b[hcol];
          float targ = hv * (1.5957691216f + 0.0713548162f * hv * hv);
          float gv = hv * __builtin_amdgcn_rcpf(1.0f + __expf(-targ));
          hw[r * 70 + nt * 16 + l15] = f2bf(gv);
        }
    WAVE_LDS_FENCE();
    // fc2: accumulate
#pragma unroll
    for (int ks = 0; ks < 2; ++ks) {
      bf16x8 a2[2];
#pragma unroll
      for (int mt = 0; mt < 2; ++mt)
        a2[mt] = *(const bf16x8*)(&hw[(mt * 16 + l15) * 70 + ks * 32 + lhi * 8]);
#pragma unroll
      for (int nt = 0; nt < 8; ++nt) {
        bf16x8 bfr = *(const bf16x8*)(&wsB[(nt * 16 + l15) * 68 + ks * 32 + lhi * 8]);
#pragma unroll
        for (int mt = 0; mt < 2; ++mt)
          oacc[mt][nt] = MFMA(a2[mt], bfr, oacc[mt][nt]);
      }
    }
    WAVE_LDS_FENCE();
    __syncthreads();
  }
#pragma unroll
  for (int mt = 0; mt < 2; ++mt)
#pragma unroll
    for (int nt = 0; nt < 8; ++nt)
#pragma unroll
      for (int j = 0; j < 4; ++j) {
        int r = mbase + mt * 16 + lhi * 4 + j;
        out[(size_t)r * 128 + nt * 16 + l15] = oacc[mt][nt][j] + fc2_b[nt * 16 + l15];
      }
}

// ---------------------------------------------------------------------------
extern "C" void kernel_launch(void* const* d_in, const int* in_sizes, int n_in,
                              void* d_out, int out_size, void* d_ws, size_t ws_size,
                              hipStream_t stream) {
  const float* x      = (const float*)d_in[0];
  const float* mask   = (const float*)d_in[1];
  const int*   rel    = (const int*)d_in[2];
  const float* n1g    = (const float*)d_in[3];
  const float* n1b    = (const float*)d_in[4];
  const float* qkv_w  = (const float*)d_in[5];
  const float* qkv_b  = (const float*)d_in[6];
  const float* rpb    = (const float*)d_in[7];
  const float* proj_w = (const float*)d_in[8];
  const float* proj_b = (const float*)d_in[9];
  const float* n2g    = (const float*)d_in[10];
  const float* n2b    = (const float*)d_in[11];
  const float* fc1_w  = (const float*)d_in[12];
  const float* fc1_b  = (const float*)d_in[13];
  const float* fc2_w  = (const float*)d_in[14];
  const float* fc2_b  = (const float*)d_in[15];
  float* out = (float*)d_out;

  char* ws = (char*)d_ws;
  const size_t SZ = (size_t)NTOK * 128 * 2;
  unsigned short* win   = (unsigned short*)(ws);          // ao scratch
  unsigned short* qb    = (unsigned short*)(ws + SZ);
  unsigned short* kb    = (unsigned short*)(ws + 2 * SZ);
  unsigned short* vb    = (unsigned short*)(ws + 3 * SZ);
  unsigned short* qkvT  = (unsigned short*)(ws + 4 * SZ);
  unsigned short* projT = qkvT + 384 * 128;
  unsigned short* fc1T  = projT + 128 * 128;
  unsigned short* fc2T  = fc1T + 512 * 128;
  unsigned short* cmb   = fc2T + 128 * 512;     // 4*256*9604 bf16 = 19.7 MB
  float* qbb            = (float*)(cmb + (size_t)4 * 256 * NN);
  unsigned short* ao = win;
  unsigned short* zb = qb;

  k0_prep<<<256, 256, 0, stream>>>(qkv_w, proj_w, fc1_w, fc2_w, n1g, n1b, qkv_b,
                                   qkvT, projT, fc1T, fc2T, qbb);
  k0b_cmb<<<(4 * 256 * NN + 255) / 256, 256, 0, stream>>>(rel, rpb, mask, cmb);
  k2_qkv<<<NTOK / 128, 256, 0, stream>>>(x, qkvT, qbb, qb, kb, vb);
  k3_attn<<<NWIN * 4, 512, 0, stream>>>(qb, kb, vb, cmb, ao);
  k4_proj_ln<<<NTOK / 128, 256, 0, stream>>>(ao, projT, proj_b, x, n2g, n2b, zb);
  k5_mlp<<<NTOK / 128, 256, 0, stream>>>(zb, fc1T, fc1_b, fc2T, fc2_b, out);
}

// Round 8
// 409.239 us; speedup vs baseline: 1.4029x; 1.0672x over previous
//
#include <hip/hip_runtime.h>
#include <hip/hip_bf16.h>

typedef __attribute__((ext_vector_type(8))) short bf16x8;
typedef __attribute__((ext_vector_type(4))) float f32x4;

#define MFMA(a,b,c) __builtin_amdgcn_mfma_f32_16x16x32_bf16((a),(b),(c),0,0,0)
#define WAVE_LDS_FENCE() do { asm volatile("s_waitcnt lgkmcnt(0)" ::: "memory"); \
                              __builtin_amdgcn_sched_barrier(0); } while (0)

static constexpr int NTOK = 8 * 8 * 56 * 56;   // 200704 tokens
static constexpr int NT   = 98;                // tokens per window
static constexpr int NWIN = 2048;              // total windows
static constexpr int NN   = NT * NT;           // 9604

__device__ __forceinline__ unsigned short f2bf(float f) {
  unsigned r;
  asm("v_cvt_pk_bf16_f32 %0, %1, %1" : "=v"(r) : "v"(f));
  return (unsigned short)r;
}
__device__ __forceinline__ unsigned f2bf2(float lo, float hi) {
  unsigned r;
  asm("v_cvt_pk_bf16_f32 %0, %1, %2" : "=v"(r) : "v"(lo), "v"(hi));
  return r;
}
__device__ __forceinline__ float bf2f(unsigned short s) {
  union { unsigned u; float f; } v; v.u = ((unsigned)s) << 16; return v.f;
}
union U8 { unsigned u[4]; bf16x8 v; };

// map window-token t -> spatial row index (shifted partition)
__device__ __forceinline__ size_t srow_of(int t) {
  int widx = t / NT, n = t - widx * NT;
  int bb = widx >> 8, wb = widx & 255;
  int dW = wb >> 6, hW = (wb >> 3) & 7, wW = wb & 7;
  int dr = n / 49, rem = n - dr * 49, hr = rem / 7, wr = rem - hr * 7;
  int dsh = (dW * 2 + dr + 1) & 7;
  int hs = hW * 7 + hr + 3; if (hs >= 56) hs -= 56;
  int wsv = wW * 7 + wr + 3; if (wsv >= 56) wsv -= 56;
  return ((size_t)(bb * 8 + dsh) * 56 + hs) * 56 + wsv;
}

// ---------------- K0: weight transpose + bf16 cast + LN1 fold --------------
__global__ __launch_bounds__(256) void k0_prep(
    const float* __restrict__ qkv_w, const float* __restrict__ proj_w,
    const float* __restrict__ fc1_w, const float* __restrict__ fc2_w,
    const float* __restrict__ n1g, const float* __restrict__ n1b,
    const float* __restrict__ qkv_b,
    unsigned short* __restrict__ qkvT, unsigned short* __restrict__ projT,
    unsigned short* __restrict__ fc1T, unsigned short* __restrict__ fc2T,
    float* __restrict__ qbb) {
  int idx = blockIdx.x * 256 + threadIdx.x;
  if (idx < 384 * 128) { int n = idx >> 7, k = idx & 127; qkvT[idx] = f2bf(qkv_w[k * 384 + n] * n1g[k]); }
  if (idx < 128 * 128) { int n = idx >> 7, k = idx & 127; projT[idx] = f2bf(proj_w[k * 128 + n]); }
  if (idx < 512 * 128) { int n = idx >> 7, k = idx & 127; fc1T[idx] = f2bf(fc1_w[k * 512 + n]); }
  if (idx < 128 * 512) { int n = idx >> 9, k = idx & 511; fc2T[idx] = f2bf(fc2_w[k * 128 + n]); }
  if (idx < 384) {
    float acc = qkv_b[idx];
    for (int k = 0; k < 128; ++k) acc += n1b[k] * qkv_w[k * 384 + idx];
    qbb[idx] = acc;
  }
}

// ---------------- K0b: combined bias+mask table, bf16 ----------------------
__global__ __launch_bounds__(256) void k0b_cmb(
    const int* __restrict__ rel, const float* __restrict__ rpb,
    const float* __restrict__ mask, unsigned short* __restrict__ cmb) {
  int idx = blockIdx.x * 256 + threadIdx.x;
  if (idx >= 4 * 256 * NN) return;
  int h = idx / (256 * NN);
  int rem = idx - h * 256 * NN;
  int wb = rem / NN, r = rem - wb * NN;
  cmb[idx] = f2bf(rpb[rel[r] * 4 + h] + mask[(size_t)wb * NN + r]);
}

// ---------------- K2: fused LN1 + shift/partition + QKV GEMM ---------------
__global__ __launch_bounds__(256, 2) void k2_qkv(
    const float* __restrict__ x, const unsigned short* __restrict__ qkvT,
    const float* __restrict__ qbb,
    unsigned short* __restrict__ q, unsigned short* __restrict__ k,
    unsigned short* __restrict__ v) {
  __shared__ __align__(16) unsigned short wsW[64 * 136];   // 17408 B
  int tid = threadIdx.x, wv = tid >> 6, lane = tid & 63;
  int l15 = lane & 15, lhi = lane >> 4;
  int mbase = blockIdx.x * 128 + wv * 32;

  bf16x8 afr[2][4];
#pragma unroll
  for (int mt = 0; mt < 2; ++mt) {
    int row = mbase + mt * 16 + l15;
    size_t srow = srow_of(row);
    const float* xr = x + srow * 128 + lhi * 8;
    float xv[4][8];
    float s = 0.f, ss = 0.f;
#pragma unroll
    for (int ks = 0; ks < 4; ++ks) {
      float4 lo = *(const float4*)(xr + ks * 32);
      float4 hi = *(const float4*)(xr + ks * 32 + 4);
      xv[ks][0] = lo.x; xv[ks][1] = lo.y; xv[ks][2] = lo.z; xv[ks][3] = lo.w;
      xv[ks][4] = hi.x; xv[ks][5] = hi.y; xv[ks][6] = hi.z; xv[ks][7] = hi.w;
#pragma unroll
      for (int e = 0; e < 8; ++e) { s += xv[ks][e]; ss += xv[ks][e] * xv[ks][e]; }
    }
    s += __shfl_xor(s, 16);  ss += __shfl_xor(ss, 16);
    s += __shfl_xor(s, 32);  ss += __shfl_xor(ss, 32);
    float mu = s * (1.f / 128.f);
    float var = ss * (1.f / 128.f) - mu * mu;
    float inv = __builtin_amdgcn_rsqf(var + 1e-5f);
#pragma unroll
    for (int ks = 0; ks < 4; ++ks) {
      U8 t;
#pragma unroll
      for (int p = 0; p < 4; ++p)
        t.u[p] = f2bf2((xv[ks][2 * p] - mu) * inv, (xv[ks][2 * p + 1] - mu) * inv);
      afr[mt][ks] = t.v;
    }
  }

  int rbase[2][4];
#pragma unroll
  for (int mt = 0; mt < 2; ++mt)
#pragma unroll
    for (int j = 0; j < 4; ++j) {
      int r = mbase + mt * 16 + lhi * 4 + j;
      int widx = r / NT, n = r - widx * NT;
      rbase[mt][j] = widx * 392 + n;
    }

  bf16x8 pf[4];
#pragma unroll
  for (int u = 0; u < 4; ++u) pf[u] = *(const bf16x8*)(qkvT + u * 2048 + tid * 8);

  for (int ch = 0; ch < 6; ++ch) {
#pragma unroll
    for (int u = 0; u < 4; ++u) {
      int flat = u * 2048 + tid * 8;
      *(bf16x8*)(&wsW[(flat >> 7) * 136 + (flat & 127)]) = pf[u];
    }
    __syncthreads();
    if (ch < 5) {
#pragma unroll
      for (int u = 0; u < 4; ++u)
        pf[u] = *(const bf16x8*)(qkvT + (ch + 1) * 8192 + u * 2048 + tid * 8);
    }
    f32x4 acc[2][4] = {};
#pragma unroll
    for (int ks = 0; ks < 4; ++ks)
#pragma unroll
      for (int nt = 0; nt < 4; ++nt) {
        bf16x8 bfr = *(const bf16x8*)(&wsW[(nt * 16 + l15) * 136 + ks * 32 + lhi * 8]);
#pragma unroll
        for (int mt = 0; mt < 2; ++mt)
          acc[mt][nt] = MFMA(afr[mt][ks], bfr, acc[mt][nt]);
      }
#pragma unroll
    for (int nt = 0; nt < 4; ++nt) {
      int col = ch * 64 + nt * 16 + l15;
      int which = col >> 7, head = (col >> 5) & 3, hd = col & 31;
      unsigned short* outb = which == 0 ? q : (which == 1 ? k : v);
      float scale = which == 0 ? 0.17677669529663687f : 1.0f;
      float bias = qbb[col];
#pragma unroll
      for (int mt = 0; mt < 2; ++mt)
#pragma unroll
        for (int j = 0; j < 4; ++j) {
          float val = (acc[mt][nt][j] + bias) * scale;
          outb[(size_t)(rbase[mt][j] + head * 98) * 32 + hd] = f2bf(val);
        }
    }
    __syncthreads();
  }
}

// ---------------- K3: window attention, 512 thr, one 16-row tile per wave --
__global__ __launch_bounds__(512) void k3_attn(
    const unsigned short* __restrict__ q, const unsigned short* __restrict__ kk,
    const unsigned short* __restrict__ vv, const unsigned short* __restrict__ cmb,
    unsigned short* __restrict__ out) {
  __shared__ __align__(16) unsigned short Vt[32 * 140];    // 8960 B
  __shared__ __align__(16) unsigned short Pw[7][16 * 140]; // 31360 B
  int bid = blockIdx.x;
  int widx = bid >> 2, head = bid & 3;
  int wb = widx & 255;
  size_t base = (size_t)(widx * 4 + head) * NT * 32;
  int tid = threadIdx.x, wv = tid >> 6, lane = tid & 63;
  int l15 = lane & 15, lhi = lane >> 4;

  for (int idx = tid; idx < NT * 32; idx += 512) {
    int j = idx >> 5, d = idx & 31;
    Vt[d * 140 + j] = vv[base + idx];
  }
  for (int idx = tid; idx < 32 * 30; idx += 512) {
    int d = idx / 30, j = 98 + idx % 30;
    Vt[d * 140 + j] = 0;
  }
  __syncthreads();
  if (wv >= 7) return;           // no barriers after this point

  const unsigned short* cw = cmb + ((size_t)(head << 8) + wb) * NN;
  unsigned short* P = Pw[wv];
  int mb = wv * 16;

  bf16x8 afr = *(const bf16x8*)(q + base + (size_t)(mb + l15) * 32 + lhi * 8);
  f32x4 sfr[7];
#pragma unroll
  for (int nt = 0; nt < 7; ++nt) {
    bf16x8 bfr = *(const bf16x8*)(kk + base + (size_t)(nt * 16 + l15) * 32 + lhi * 8);
    f32x4 zz = {};
    sfr[nt] = MFMA(afr, bfr, zz);
  }
#pragma unroll
  for (int j = 0; j < 4; ++j) {
    int i = mb + lhi * 4 + j;
    int ic = i < 97 ? i : 97;
    float sv[7];
#pragma unroll
    for (int nt = 0; nt < 7; ++nt) {
      int colc = nt * 16 + l15;
      int jc = colc < 97 ? colc : 97;
      float s = fminf(fmaxf(sfr[nt][j], -1e4f), 1e4f);
      float bm = bf2f(cw[ic * NT + jc]);
      sv[nt] = (i < NT && colc < NT) ? (s + bm) : -1e30f;
    }
    float mx = sv[0];
#pragma unroll
    for (int nt = 1; nt < 7; ++nt) mx = fmaxf(mx, sv[nt]);
#pragma unroll
    for (int m2 = 1; m2 < 16; m2 <<= 1) mx = fmaxf(mx, __shfl_xor(mx, m2));
    float sum = 0.f, p[7];
#pragma unroll
    for (int nt = 0; nt < 7; ++nt) { p[nt] = __expf(sv[nt] - mx); sum += p[nt]; }
#pragma unroll
    for (int m2 = 1; m2 < 16; m2 <<= 1) sum += __shfl_xor(sum, m2);
    float inv = __builtin_amdgcn_rcpf(sum);
    int iloc = lhi * 4 + j;
#pragma unroll
    for (int nt = 0; nt < 7; ++nt)
      P[iloc * 140 + nt * 16 + l15] = f2bf(p[nt] * inv);
    P[iloc * 140 + 112 + l15] = 0;
  }
  WAVE_LDS_FENCE();

  f32x4 ofr[2] = {};
#pragma unroll
  for (int ks = 0; ks < 4; ++ks) {
    bf16x8 pafr = *(const bf16x8*)(P + l15 * 140 + ks * 32 + lhi * 8);
#pragma unroll
    for (int nt = 0; nt < 2; ++nt) {
      bf16x8 bfr = *(const bf16x8*)(Vt + (nt * 16 + l15) * 140 + ks * 32 + lhi * 8);
      ofr[nt] = MFMA(pafr, bfr, ofr[nt]);
    }
  }
#pragma unroll
  for (int nt = 0; nt < 2; ++nt)
#pragma unroll
    for (int j = 0; j < 4; ++j) {
      int n = mb + lhi * 4 + j;
      if (n < NT) {
        int d = nt * 16 + l15;
        out[(size_t)(widx * NT + n) * 128 + head * 32 + d] = f2bf(ofr[nt][j]);
      }
    }
}

// ---------------- K4: proj + reverse/unshift + residual + LN2 --------------
// epilogue via LDS bounce (wsW reused): vectorized x loads / z stores
__global__ __launch_bounds__(256, 3) void k4_proj_ln(
    const unsigned short* __restrict__ ao, const unsigned short* __restrict__ projT,
    const float* __restrict__ proj_b, const float* __restrict__ x,
    const float* __restrict__ g2, const float* __restrict__ b2,
    unsigned short* __restrict__ z) {
  __shared__ __align__(16) unsigned short wsW[128 * 136];   // 34816 B
  int tid = threadIdx.x, wv = tid >> 6, lane = tid & 63;
  int l15 = lane & 15, lhi = lane >> 4;
  int mbase = blockIdx.x * 128 + wv * 32;

#pragma unroll
  for (int u = 0; u < 8; ++u) {
    int flat = u * 2048 + tid * 8;
    *(bf16x8*)(&wsW[(flat >> 7) * 136 + (flat & 127)]) = *(const bf16x8*)(projT + flat);
  }
  bf16x8 afr[2][4];
#pragma unroll
  for (int mt = 0; mt < 2; ++mt)
#pragma unroll
    for (int ks = 0; ks < 4; ++ks)
      afr[mt][ks] = *(const bf16x8*)(ao + (size_t)(mbase + mt * 16 + l15) * 128 + ks * 32 + lhi * 8);
  __syncthreads();

  f32x4 acc[2][8] = {};
#pragma unroll
  for (int ks = 0; ks < 4; ++ks)
#pragma unroll
    for (int nt = 0; nt < 8; ++nt) {
      bf16x8 bfr = *(const bf16x8*)(&wsW[(nt * 16 + l15) * 136 + ks * 32 + lhi * 8]);
#pragma unroll
      for (int mt = 0; mt < 2; ++mt)
        acc[mt][nt] = MFMA(afr[mt][ks], bfr, acc[mt][nt]);
    }
  __syncthreads();   // all waves done reading wsW -> reuse as fp32 bounce

  float* bounce = (float*)wsW + wv * (16 * 132);  // 16x132 fp32 per wave
  float pb[8];
#pragma unroll
  for (int nt = 0; nt < 8; ++nt) pb[nt] = proj_b[nt * 16 + l15];

  int rl = lane >> 2, c0 = (lane & 3) * 32;
#pragma unroll
  for (int mt = 0; mt < 2; ++mt) {
    // write fragments (+bias) into per-wave bounce tile
#pragma unroll
    for (int nt = 0; nt < 8; ++nt)
#pragma unroll
      for (int j = 0; j < 4; ++j)
        bounce[(lhi * 4 + j) * 132 + nt * 16 + l15] = acc[mt][nt][j] + pb[nt];
    WAVE_LDS_FENCE();

    // lane owns row rl (global t), 32 contiguous channels at c0
    int t = mbase + mt * 16 + rl;
    size_t srow = srow_of(t);
    const float* xr = x + srow * 128 + c0;
    float vals[32];
    float s = 0.f, ss = 0.f;
#pragma unroll
    for (int i = 0; i < 8; ++i) {
      float4 pv = *(const float4*)(bounce + rl * 132 + c0 + 4 * i);
      float4 xv = *(const float4*)(xr + 4 * i);
      float a0 = pv.x + xv.x, a1 = pv.y + xv.y, a2 = pv.z + xv.z, a3 = pv.w + xv.w;
      vals[4 * i] = a0; vals[4 * i + 1] = a1; vals[4 * i + 2] = a2; vals[4 * i + 3] = a3;
      s += a0 + a1 + a2 + a3;
      ss += a0 * a0 + a1 * a1 + a2 * a2 + a3 * a3;
    }
    s += __shfl_xor(s, 1);  ss += __shfl_xor(ss, 1);
    s += __shfl_xor(s, 2);  ss += __shfl_xor(ss, 2);
    float mu = s * (1.f / 128.f);
    float var = ss * (1.f / 128.f) - mu * mu;
    float inv = __builtin_amdgcn_rsqf(var + 1e-5f);
    unsigned pk[16];
#pragma unroll
    for (int i = 0; i < 8; ++i) {
      float4 g = *(const float4*)(g2 + c0 + 4 * i);
      float4 b = *(const float4*)(b2 + c0 + 4 * i);
      pk[2 * i]     = f2bf2((vals[4 * i]     - mu) * inv * g.x + b.x,
                            (vals[4 * i + 1] - mu) * inv * g.y + b.y);
      pk[2 * i + 1] = f2bf2((vals[4 * i + 2] - mu) * inv * g.z + b.z,
                            (vals[4 * i + 3] - mu) * inv * g.w + b.w);
    }
    unsigned* zp = (unsigned*)(z + srow * 128 + c0);
#pragma unroll
    for (int i = 0; i < 4; ++i)
      *(uint4*)(zp + 4 * i) = make_uint4(pk[4 * i], pk[4 * i + 1], pk[4 * i + 2], pk[4 * i + 3]);
    WAVE_LDS_FENCE();   // reads done before next mt overwrites bounce
  }
}

// ---------------- K5: MLP fc1 + GELU + fc2, 512 thr / 256 rows -------------
// (512,2): VGPR cap 256 (R5's failure was the cap, not the block size)
__global__ __launch_bounds__(512, 2) void k5_mlp(
    const unsigned short* __restrict__ z, const unsigned short* __restrict__ fc1T,
    const float* __restrict__ fc1_b, const unsigned short* __restrict__ fc2T,
    const float* __restrict__ fc2_b, float* __restrict__ out) {
  __shared__ __align__(16) unsigned short wsA[64 * 132];   // 16896 B
  __shared__ __align__(16) unsigned short wsB[128 * 68];   // 17408 B
  __shared__ __align__(16) unsigned short hl[8][32 * 70];  // 35840 B
  int tid = threadIdx.x, wv = tid >> 6, lane = tid & 63;
  int l15 = lane & 15, lhi = lane >> 4;
  int mbase = blockIdx.x * 256 + wv * 32;
  unsigned short* hw = hl[wv];

  bf16x8 afr[2][4];
#pragma unroll
  for (int mt = 0; mt < 2; ++mt)
#pragma unroll
    for (int ks = 0; ks < 4; ++ks)
      afr[mt][ks] = *(const bf16x8*)(z + (size_t)(mbase + mt * 16 + l15) * 128 + ks * 32 + lhi * 8);

  bf16x8 pfA[2], pfB[2];
#pragma unroll
  for (int u = 0; u < 2; ++u) pfA[u] = *(const bf16x8*)(fc1T + u * 4096 + tid * 8);
#pragma unroll
  for (int u = 0; u < 2; ++u) {
    int flat = u * 4096 + tid * 8;
    pfB[u] = *(const bf16x8*)(fc2T + (size_t)(flat >> 6) * 512 + (flat & 63));
  }

  f32x4 oacc[2][8] = {};
  for (int ch = 0; ch < 8; ++ch) {
#pragma unroll
    for (int u = 0; u < 2; ++u) {
      int flat = u * 4096 + tid * 8;
      *(bf16x8*)(&wsA[(flat >> 7) * 132 + (flat & 127)]) = pfA[u];
      *(bf16x8*)(&wsB[(flat >> 6) * 68 + (flat & 63)]) = pfB[u];
    }
    __syncthreads();
    if (ch < 7) {
#pragma unroll
      for (int u = 0; u < 2; ++u)
        pfA[u] = *(const bf16x8*)(fc1T + (ch + 1) * 8192 + u * 4096 + tid * 8);
#pragma unroll
      for (int u = 0; u < 2; ++u) {
        int flat = u * 4096 + tid * 8;
        pfB[u] = *(const bf16x8*)(fc2T + (size_t)(flat >> 6) * 512 + (ch + 1) * 64 + (flat & 63));
      }
    }
    // fc1: h[32 x 64] per wave
    f32x4 hacc[2][4] = {};
#pragma unroll
    for (int ks = 0; ks < 4; ++ks)
#pragma unroll
      for (int nt = 0; nt < 4; ++nt) {
        bf16x8 bfr = *(const bf16x8*)(&wsA[(nt * 16 + l15) * 132 + ks * 32 + lhi * 8]);
#pragma unroll
        for (int mt = 0; mt < 2; ++mt)
          hacc[mt][nt] = MFMA(afr[mt][ks], bfr, hacc[mt][nt]);
      }
#pragma unroll
    for (int mt = 0; mt < 2; ++mt)
#pragma unroll
      for (int nt = 0; nt < 4; ++nt)
#pragma unroll
        for (int j = 0; j < 4; ++j) {
          int r = mt * 16 + lhi * 4 + j;
          int hcol = ch * 64 + nt * 16 + l15;
          float hv = hacc[mt][nt][j] + fc1_b[hcol];
          float targ = hv * (1.5957691216f + 0.0713548162f * hv * hv);
          float gv = hv * __builtin_amdgcn_rcpf(1.0f + __expf(-targ));
          hw[r * 70 + nt * 16 + l15] = f2bf(gv);
        }
    WAVE_LDS_FENCE();
    // fc2: accumulate
#pragma unroll
    for (int ks = 0; ks < 2; ++ks) {
      bf16x8 a2[2];
#pragma unroll
      for (int mt = 0; mt < 2; ++mt)
        a2[mt] = *(const bf16x8*)(&hw[(mt * 16 + l15) * 70 + ks * 32 + lhi * 8]);
#pragma unroll
      for (int nt = 0; nt < 8; ++nt) {
        bf16x8 bfr = *(const bf16x8*)(&wsB[(nt * 16 + l15) * 68 + ks * 32 + lhi * 8]);
#pragma unroll
        for (int mt = 0; mt < 2; ++mt)
          oacc[mt][nt] = MFMA(a2[mt], bfr, oacc[mt][nt]);
      }
    }
    WAVE_LDS_FENCE();
    __syncthreads();
  }
#pragma unroll
  for (int mt = 0; mt < 2; ++mt)
#pragma unroll
    for (int nt = 0; nt < 8; ++nt)
#pragma unroll
      for (int j = 0; j < 4; ++j) {
        int r = mbase + mt * 16 + lhi * 4 + j;
        out[(size_t)r * 128 + nt * 16 + l15] = oacc[mt][nt][j] + fc2_b[nt * 16 + l15];
      }
}

// ---------------------------------------------------------------------------
extern "C" void kernel_launch(void* const* d_in, const int* in_sizes, int n_in,
                              void* d_out, int out_size, void* d_ws, size_t ws_size,
                              hipStream_t stream) {
  const float* x      = (const float*)d_in[0];
  const float* mask   = (const float*)d_in[1];
  const int*   rel    = (const int*)d_in[2];
  const float* n1g    = (const float*)d_in[3];
  const float* n1b    = (const float*)d_in[4];
  const float* qkv_w  = (const float*)d_in[5];
  const float* qkv_b  = (const float*)d_in[6];
  const float* rpb    = (const float*)d_in[7];
  const float* proj_w = (const float*)d_in[8];
  const float* proj_b = (const float*)d_in[9];
  const float* n2g    = (const float*)d_in[10];
  const float* n2b    = (const float*)d_in[11];
  const float* fc1_w  = (const float*)d_in[12];
  const float* fc1_b  = (const float*)d_in[13];
  const float* fc2_w  = (const float*)d_in[14];
  const float* fc2_b  = (const float*)d_in[15];
  float* out = (float*)d_out;

  char* ws = (char*)d_ws;
  const size_t SZ = (size_t)NTOK * 128 * 2;
  unsigned short* win   = (unsigned short*)(ws);          // ao scratch
  unsigned short* qb    = (unsigned short*)(ws + SZ);
  unsigned short* kb    = (unsigned short*)(ws + 2 * SZ);
  unsigned short* vb    = (unsigned short*)(ws + 3 * SZ);
  unsigned short* qkvT  = (unsigned short*)(ws + 4 * SZ);
  unsigned short* projT = qkvT + 384 * 128;
  unsigned short* fc1T  = projT + 128 * 128;
  unsigned short* fc2T  = fc1T + 512 * 128;
  unsigned short* cmb   = fc2T + 128 * 512;     // 4*256*9604 bf16 = 19.7 MB
  float* qbb            = (float*)(cmb + (size_t)4 * 256 * NN);
  unsigned short* ao = win;
  unsigned short* zb = qb;

  k0_prep<<<256, 256, 0, stream>>>(qkv_w, proj_w, fc1_w, fc2_w, n1g, n1b, qkv_b,
                                   qkvT, projT, fc1T, fc2T, qbb);
  k0b_cmb<<<(4 * 256 * NN + 255) / 256, 256, 0, stream>>>(rel, rpb, mask, cmb);
  k2_qkv<<<NTOK / 128, 256, 0, stream>>>(x, qkvT, qbb, qb, kb, vb);
  k3_attn<<<NWIN * 4, 512, 0, stream>>>(qb, kb, vb, cmb, ao);
  k4_proj_ln<<<NTOK / 128, 256, 0, stream>>>(ao, projT, proj_b, x, n2g, n2b, zb);
  k5_mlp<<<NTOK / 256, 512, 0, stream>>>(zb, fc1T, fc1_b, fc2T, fc2_b, out);
}

// Round 9
// 355.476 us; speedup vs baseline: 1.6151x; 1.1512x over previous
//
#include <hip/hip_runtime.h>
#include <hip/hip_bf16.h>

typedef __attribute__((ext_vector_type(8))) short bf16x8;
typedef __attribute__((ext_vector_type(4))) float f32x4;

#define MFMA(a,b,c) __builtin_amdgcn_mfma_f32_16x16x32_bf16((a),(b),(c),0,0,0)
#define WAVE_LDS_FENCE() do { asm volatile("s_waitcnt lgkmcnt(0)" ::: "memory"); \
                              __builtin_amdgcn_sched_barrier(0); } while (0)

static constexpr int NTOK = 8 * 8 * 56 * 56;   // 200704 tokens
static constexpr int NT   = 98;                // tokens per window
static constexpr int NWIN = 2048;              // total windows
static constexpr int NN   = NT * NT;           // 9604

__device__ __forceinline__ unsigned short f2bf(float f) {
  unsigned r;
  asm("v_cvt_pk_bf16_f32 %0, %1, %1" : "=v"(r) : "v"(f));
  return (unsigned short)r;
}
__device__ __forceinline__ unsigned f2bf2(float lo, float hi) {
  unsigned r;
  asm("v_cvt_pk_bf16_f32 %0, %1, %2" : "=v"(r) : "v"(lo), "v"(hi));
  return r;
}
__device__ __forceinline__ float bf2f(unsigned short s) {
  union { unsigned u; float f; } v; v.u = ((unsigned)s) << 16; return v.f;
}
union U8 { unsigned u[4]; bf16x8 v; };

// map window-token t -> spatial row index (shifted partition)
__device__ __forceinline__ size_t srow_of(int t) {
  int widx = t / NT, n = t - widx * NT;
  int bb = widx >> 8, wb = widx & 255;
  int dW = wb >> 6, hW = (wb >> 3) & 7, wW = wb & 7;
  int dr = n / 49, rem = n - dr * 49, hr = rem / 7, wr = rem - hr * 7;
  int dsh = (dW * 2 + dr + 1) & 7;
  int hs = hW * 7 + hr + 3; if (hs >= 56) hs -= 56;
  int wsv = wW * 7 + wr + 3; if (wsv >= 56) wsv -= 56;
  return ((size_t)(bb * 8 + dsh) * 56 + hs) * 56 + wsv;
}

// ---------------- K0: weight transpose + bf16 cast + LN1 fold --------------
__global__ __launch_bounds__(256) void k0_prep(
    const float* __restrict__ qkv_w, const float* __restrict__ proj_w,
    const float* __restrict__ fc1_w, const float* __restrict__ fc2_w,
    const float* __restrict__ n1g, const float* __restrict__ n1b,
    const float* __restrict__ qkv_b,
    unsigned short* __restrict__ qkvT, unsigned short* __restrict__ projT,
    unsigned short* __restrict__ fc1T, unsigned short* __restrict__ fc2T,
    float* __restrict__ qbb) {
  int idx = blockIdx.x * 256 + threadIdx.x;
  if (idx < 384 * 128) { int n = idx >> 7, k = idx & 127; qkvT[idx] = f2bf(qkv_w[k * 384 + n] * n1g[k]); }
  if (idx < 128 * 128) { int n = idx >> 7, k = idx & 127; projT[idx] = f2bf(proj_w[k * 128 + n]); }
  if (idx < 512 * 128) { int n = idx >> 7, k = idx & 127; fc1T[idx] = f2bf(fc1_w[k * 512 + n]); }
  if (idx < 128 * 512) { int n = idx >> 9, k = idx & 511; fc2T[idx] = f2bf(fc2_w[k * 128 + n]); }
  if (idx < 384) {
    float acc = qkv_b[idx];
    for (int k = 0; k < 128; ++k) acc += n1b[k] * qkv_w[k * 384 + idx];
    qbb[idx] = acc;
  }
}

// ---------------- K0b: combined bias+mask table, 8 mask classes ------------
// only 8 distinct mask patterns (split iff dW==3 / hW==7 / wW==7);
// read ground truth from representative windows
__global__ __launch_bounds__(256) void k0b_cmb(
    const int* __restrict__ rel, const float* __restrict__ rpb,
    const float* __restrict__ mask, unsigned short* __restrict__ cmb) {
  int idx = blockIdx.x * 256 + threadIdx.x;
  if (idx >= 4 * 8 * NN) return;
  int h = idx / (8 * NN);
  int rem = idx - h * 8 * NN;
  int cls = rem / NN, r = rem - cls * NN;
  int wb_rep = ((cls >> 2) & 1 ? 192 : 0) + ((cls >> 1) & 1 ? 56 : 0) + ((cls & 1) ? 7 : 0);
  cmb[idx] = f2bf(rpb[rel[r] * 4 + h] + mask[(size_t)wb_rep * NN + r]);
}

// ---------------- K2: fused LN1 + shift/partition + QKV GEMM ---------------
__global__ __launch_bounds__(256, 2) void k2_qkv(
    const float* __restrict__ x, const unsigned short* __restrict__ qkvT,
    const float* __restrict__ qbb,
    unsigned short* __restrict__ q, unsigned short* __restrict__ k,
    unsigned short* __restrict__ v) {
  __shared__ __align__(16) unsigned short wsW[64 * 136];   // 17408 B
  int tid = threadIdx.x, wv = tid >> 6, lane = tid & 63;
  int l15 = lane & 15, lhi = lane >> 4;
  int mbase = blockIdx.x * 128 + wv * 32;

  bf16x8 afr[2][4];
#pragma unroll
  for (int mt = 0; mt < 2; ++mt) {
    int row = mbase + mt * 16 + l15;
    size_t srow = srow_of(row);
    const float* xr = x + srow * 128 + lhi * 8;
    float xv[4][8];
    float s = 0.f, ss = 0.f;
#pragma unroll
    for (int ks = 0; ks < 4; ++ks) {
      float4 lo = *(const float4*)(xr + ks * 32);
      float4 hi = *(const float4*)(xr + ks * 32 + 4);
      xv[ks][0] = lo.x; xv[ks][1] = lo.y; xv[ks][2] = lo.z; xv[ks][3] = lo.w;
      xv[ks][4] = hi.x; xv[ks][5] = hi.y; xv[ks][6] = hi.z; xv[ks][7] = hi.w;
#pragma unroll
      for (int e = 0; e < 8; ++e) { s += xv[ks][e]; ss += xv[ks][e] * xv[ks][e]; }
    }
    s += __shfl_xor(s, 16);  ss += __shfl_xor(ss, 16);
    s += __shfl_xor(s, 32);  ss += __shfl_xor(ss, 32);
    float mu = s * (1.f / 128.f);
    float var = ss * (1.f / 128.f) - mu * mu;
    float inv = __builtin_amdgcn_rsqf(var + 1e-5f);
#pragma unroll
    for (int ks = 0; ks < 4; ++ks) {
      U8 t;
#pragma unroll
      for (int p = 0; p < 4; ++p)
        t.u[p] = f2bf2((xv[ks][2 * p] - mu) * inv, (xv[ks][2 * p + 1] - mu) * inv);
      afr[mt][ks] = t.v;
    }
  }

  int rbase[2][4];
#pragma unroll
  for (int mt = 0; mt < 2; ++mt)
#pragma unroll
    for (int j = 0; j < 4; ++j) {
      int r = mbase + mt * 16 + lhi * 4 + j;
      int widx = r / NT, n = r - widx * NT;
      rbase[mt][j] = widx * 392 + n;
    }

  bf16x8 pf[4];
#pragma unroll
  for (int u = 0; u < 4; ++u) pf[u] = *(const bf16x8*)(qkvT + u * 2048 + tid * 8);

  for (int ch = 0; ch < 6; ++ch) {
#pragma unroll
    for (int u = 0; u < 4; ++u) {
      int flat = u * 2048 + tid * 8;
      *(bf16x8*)(&wsW[(flat >> 7) * 136 + (flat & 127)]) = pf[u];
    }
    __syncthreads();
    if (ch < 5) {
#pragma unroll
      for (int u = 0; u < 4; ++u)
        pf[u] = *(const bf16x8*)(qkvT + (ch + 1) * 8192 + u * 2048 + tid * 8);
    }
    f32x4 acc[2][4] = {};
#pragma unroll
    for (int ks = 0; ks < 4; ++ks)
#pragma unroll
      for (int nt = 0; nt < 4; ++nt) {
        bf16x8 bfr = *(const bf16x8*)(&wsW[(nt * 16 + l15) * 136 + ks * 32 + lhi * 8]);
#pragma unroll
        for (int mt = 0; mt < 2; ++mt)
          acc[mt][nt] = MFMA(afr[mt][ks], bfr, acc[mt][nt]);
      }
#pragma unroll
    for (int nt = 0; nt < 4; ++nt) {
      int col = ch * 64 + nt * 16 + l15;
      int which = col >> 7, head = (col >> 5) & 3, hd = col & 31;
      unsigned short* outb = which == 0 ? q : (which == 1 ? k : v);
      float scale = which == 0 ? 0.17677669529663687f : 1.0f;
      float bias = qbb[col];
#pragma unroll
      for (int mt = 0; mt < 2; ++mt)
#pragma unroll
        for (int j = 0; j < 4; ++j) {
          float val = (acc[mt][nt][j] + bias) * scale;
          outb[(size_t)(rbase[mt][j] + head * 98) * 32 + hd] = f2bf(val);
        }
    }
    __syncthreads();
  }
}

// ---------------- K3: window attention, 512 thr, one 16-row tile per wave --
__global__ __launch_bounds__(512) void k3_attn(
    const unsigned short* __restrict__ q, const unsigned short* __restrict__ kk,
    const unsigned short* __restrict__ vv, const unsigned short* __restrict__ cmb,
    unsigned short* __restrict__ out) {
  __shared__ __align__(16) unsigned short Vt[32 * 140];    // 8960 B
  __shared__ __align__(16) unsigned short Pw[7][16 * 140]; // 31360 B
  int bid = blockIdx.x;
  int widx = bid >> 2, head = bid & 3;
  int wb = widx & 255;
  size_t base = (size_t)(widx * 4 + head) * NT * 32;
  int tid = threadIdx.x, wv = tid >> 6, lane = tid & 63;
  int l15 = lane & 15, lhi = lane >> 4;

  for (int idx = tid; idx < NT * 32; idx += 512) {
    int j = idx >> 5, d = idx & 31;
    Vt[d * 140 + j] = vv[base + idx];
  }
  for (int idx = tid; idx < 32 * 30; idx += 512) {
    int d = idx / 30, j = 98 + idx % 30;
    Vt[d * 140 + j] = 0;
  }
  __syncthreads();
  if (wv >= 7) return;           // no barriers after this point

  int cls = (((wb >> 6) == 3) << 2) | ((((wb >> 3) & 7) == 7) << 1) | ((int)((wb & 7) == 7));
  const unsigned short* cw = cmb + ((size_t)(head * 8 + cls)) * NN;
  unsigned short* P = Pw[wv];
  int mb = wv * 16;

  bf16x8 afr = *(const bf16x8*)(q + base + (size_t)(mb + l15) * 32 + lhi * 8);
  f32x4 sfr[7];
#pragma unroll
  for (int nt = 0; nt < 7; ++nt) {
    bf16x8 bfr = *(const bf16x8*)(kk + base + (size_t)(nt * 16 + l15) * 32 + lhi * 8);
    f32x4 zz = {};
    sfr[nt] = MFMA(afr, bfr, zz);
  }
#pragma unroll
  for (int j = 0; j < 4; ++j) {
    int i = mb + lhi * 4 + j;
    int ic = i < 97 ? i : 97;
    float sv[7];
#pragma unroll
    for (int nt = 0; nt < 7; ++nt) {
      int colc = nt * 16 + l15;
      int jc = colc < 97 ? colc : 97;
      float s = fminf(fmaxf(sfr[nt][j], -1e4f), 1e4f);
      float bm = bf2f(cw[ic * NT + jc]);
      sv[nt] = (i < NT && colc < NT) ? (s + bm) : -1e30f;
    }
    float mx = sv[0];
#pragma unroll
    for (int nt = 1; nt < 7; ++nt) mx = fmaxf(mx, sv[nt]);
#pragma unroll
    for (int m2 = 1; m2 < 16; m2 <<= 1) mx = fmaxf(mx, __shfl_xor(mx, m2));
    float sum = 0.f, p[7];
#pragma unroll
    for (int nt = 0; nt < 7; ++nt) { p[nt] = __expf(sv[nt] - mx); sum += p[nt]; }
#pragma unroll
    for (int m2 = 1; m2 < 16; m2 <<= 1) sum += __shfl_xor(sum, m2);
    float inv = __builtin_amdgcn_rcpf(sum);
    int iloc = lhi * 4 + j;
#pragma unroll
    for (int nt = 0; nt < 7; ++nt)
      P[iloc * 140 + nt * 16 + l15] = f2bf(p[nt] * inv);
    P[iloc * 140 + 112 + l15] = 0;
  }
  WAVE_LDS_FENCE();

  f32x4 ofr[2] = {};
#pragma unroll
  for (int ks = 0; ks < 4; ++ks) {
    bf16x8 pafr = *(const bf16x8*)(P + l15 * 140 + ks * 32 + lhi * 8);
#pragma unroll
    for (int nt = 0; nt < 2; ++nt) {
      bf16x8 bfr = *(const bf16x8*)(Vt + (nt * 16 + l15) * 140 + ks * 32 + lhi * 8);
      ofr[nt] = MFMA(pafr, bfr, ofr[nt]);
    }
  }
#pragma unroll
  for (int nt = 0; nt < 2; ++nt)
#pragma unroll
    for (int j = 0; j < 4; ++j) {
      int n = mb + lhi * 4 + j;
      if (n < NT) {
        int d = nt * 16 + l15;
        out[(size_t)(widx * NT + n) * 128 + head * 32 + d] = f2bf(ofr[nt][j]);
      }
    }
}

// ---------------- K4: proj + reverse/unshift + residual + LN2 --------------
__global__ __launch_bounds__(256, 3) void k4_proj_ln(
    const unsigned short* __restrict__ ao, const unsigned short* __restrict__ projT,
    const float* __restrict__ proj_b, const float* __restrict__ x,
    const float* __restrict__ g2, const float* __restrict__ b2,
    unsigned short* __restrict__ z) {
  __shared__ __align__(16) unsigned short wsW[128 * 136];   // 34816 B
  int tid = threadIdx.x, wv = tid >> 6, lane = tid & 63;
  int l15 = lane & 15, lhi = lane >> 4;
  int mbase = blockIdx.x * 128 + wv * 32;

#pragma unroll
  for (int u = 0; u < 8; ++u) {
    int flat = u * 2048 + tid * 8;
    *(bf16x8*)(&wsW[(flat >> 7) * 136 + (flat & 127)]) = *(const bf16x8*)(projT + flat);
  }
  bf16x8 afr[2][4];
#pragma unroll
  for (int mt = 0; mt < 2; ++mt)
#pragma unroll
    for (int ks = 0; ks < 4; ++ks)
      afr[mt][ks] = *(const bf16x8*)(ao + (size_t)(mbase + mt * 16 + l15) * 128 + ks * 32 + lhi * 8);
  __syncthreads();

  f32x4 acc[2][8] = {};
#pragma unroll
  for (int ks = 0; ks < 4; ++ks)
#pragma unroll
    for (int nt = 0; nt < 8; ++nt) {
      bf16x8 bfr = *(const bf16x8*)(&wsW[(nt * 16 + l15) * 136 + ks * 32 + lhi * 8]);
#pragma unroll
      for (int mt = 0; mt < 2; ++mt)
        acc[mt][nt] = MFMA(afr[mt][ks], bfr, acc[mt][nt]);
    }
  __syncthreads();   // all waves done reading wsW -> reuse as fp32 bounce

  float* bounce = (float*)wsW + wv * (16 * 132);  // 16x132 fp32 per wave
  float pb[8];
#pragma unroll
  for (int nt = 0; nt < 8; ++nt) pb[nt] = proj_b[nt * 16 + l15];

  int rl = lane >> 2, c0 = (lane & 3) * 32;
#pragma unroll
  for (int mt = 0; mt < 2; ++mt) {
#pragma unroll
    for (int nt = 0; nt < 8; ++nt)
#pragma unroll
      for (int j = 0; j < 4; ++j)
        bounce[(lhi * 4 + j) * 132 + nt * 16 + l15] = acc[mt][nt][j] + pb[nt];
    WAVE_LDS_FENCE();

    int t = mbase + mt * 16 + rl;
    size_t srow = srow_of(t);
    const float* xr = x + srow * 128 + c0;
    float vals[32];
    float s = 0.f, ss = 0.f;
#pragma unroll
    for (int i = 0; i < 8; ++i) {
      float4 pv = *(const float4*)(bounce + rl * 132 + c0 + 4 * i);
      float4 xv = *(const float4*)(xr + 4 * i);
      float a0 = pv.x + xv.x, a1 = pv.y + xv.y, a2 = pv.z + xv.z, a3 = pv.w + xv.w;
      vals[4 * i] = a0; vals[4 * i + 1] = a1; vals[4 * i + 2] = a2; vals[4 * i + 3] = a3;
      s += a0 + a1 + a2 + a3;
      ss += a0 * a0 + a1 * a1 + a2 * a2 + a3 * a3;
    }
    s += __shfl_xor(s, 1);  ss += __shfl_xor(ss, 1);
    s += __shfl_xor(s, 2);  ss += __shfl_xor(ss, 2);
    float mu = s * (1.f / 128.f);
    float var = ss * (1.f / 128.f) - mu * mu;
    float inv = __builtin_amdgcn_rsqf(var + 1e-5f);
    unsigned pk[16];
#pragma unroll
    for (int i = 0; i < 8; ++i) {
      float4 g = *(const float4*)(g2 + c0 + 4 * i);
      float4 b = *(const float4*)(b2 + c0 + 4 * i);
      pk[2 * i]     = f2bf2((vals[4 * i]     - mu) * inv * g.x + b.x,
                            (vals[4 * i + 1] - mu) * inv * g.y + b.y);
      pk[2 * i + 1] = f2bf2((vals[4 * i + 2] - mu) * inv * g.z + b.z,
                            (vals[4 * i + 3] - mu) * inv * g.w + b.w);
    }
    unsigned* zp = (unsigned*)(z + srow * 128 + c0);
#pragma unroll
    for (int i = 0; i < 4; ++i)
      *(uint4*)(zp + 4 * i) = make_uint4(pk[4 * i], pk[4 * i + 1], pk[4 * i + 2], pk[4 * i + 3]);
    WAVE_LDS_FENCE();
  }
}

// ---------------- K5: MLP fc1 + GELU + fc2, 256 thr, 3 blocks/CU -----------
__global__ __launch_bounds__(256, 2) void k5_mlp(
    const unsigned short* __restrict__ z, const unsigned short* __restrict__ fc1T,
    const float* __restrict__ fc1_b, const unsigned short* __restrict__ fc2T,
    const float* __restrict__ fc2_b, float* __restrict__ out) {
  __shared__ __align__(16) unsigned short wsA[64 * 132];   // 16896 B
  __shared__ __align__(16) unsigned short wsB[128 * 68];   // 17408 B
  __shared__ __align__(16) unsigned short hl[4][32 * 70];  // 17920 B
  int tid = threadIdx.x, wv = tid >> 6, lane = tid & 63;
  int l15 = lane & 15, lhi = lane >> 4;
  int mbase = blockIdx.x * 128 + wv * 32;
  unsigned short* hw = hl[wv];

  bf16x8 afr[2][4];
#pragma unroll
  for (int mt = 0; mt < 2; ++mt)
#pragma unroll
    for (int ks = 0; ks < 4; ++ks)
      afr[mt][ks] = *(const bf16x8*)(z + (size_t)(mbase + mt * 16 + l15) * 128 + ks * 32 + lhi * 8);

  bf16x8 pfA[4], pfB[4];
#pragma unroll
  for (int u = 0; u < 4; ++u) pfA[u] = *(const bf16x8*)(fc1T + u * 2048 + tid * 8);
#pragma unroll
  for (int u = 0; u < 4; ++u) {
    int flat = u * 2048 + tid * 8;
    pfB[u] = *(const bf16x8*)(fc2T + (size_t)(flat >> 6) * 512 + (flat & 63));
  }

  f32x4 oacc[2][8] = {};
  for (int ch = 0; ch < 8; ++ch) {
#pragma unroll
    for (int u = 0; u < 4; ++u) {
      int flat = u * 2048 + tid * 8;
      *(bf16x8*)(&wsA[(flat >> 7) * 132 + (flat & 127)]) = pfA[u];
      *(bf16x8*)(&wsB[(flat >> 6) * 68 + (flat & 63)]) = pfB[u];
    }
    __syncthreads();
    if (ch < 7) {
#pragma unroll
      for (int u = 0; u < 4; ++u)
        pfA[u] = *(const bf16x8*)(fc1T + (ch + 1) * 8192 + u * 2048 + tid * 8);
#pragma unroll
      for (int u = 0; u < 4; ++u) {
        int flat = u * 2048 + tid * 8;
        pfB[u] = *(const bf16x8*)(fc2T + (size_t)(flat >> 6) * 512 + (ch + 1) * 64 + (flat & 63));
      }
    }
    f32x4 hacc[2][4] = {};
#pragma unroll
    for (int ks = 0; ks < 4; ++ks)
#pragma unroll
      for (int nt = 0; nt < 4; ++nt) {
        bf16x8 bfr = *(const bf16x8*)(&wsA[(nt * 16 + l15) * 132 + ks * 32 + lhi * 8]);
#pragma unroll
        for (int mt = 0; mt < 2; ++mt)
          hacc[mt][nt] = MFMA(afr[mt][ks], bfr, hacc[mt][nt]);
      }
#pragma unroll
    for (int mt = 0; mt < 2; ++mt)
#pragma unroll
      for (int nt = 0; nt < 4; ++nt)
#pragma unroll
        for (int j = 0; j < 4; ++j) {
          int r = mt * 16 + lhi * 4 + j;
          int hcol = ch * 64 + nt * 16 + l15;
          float hv = hacc[mt][nt][j] + fc1_b[hcol];
          float targ = hv * (1.5957691216f + 0.0713548162f * hv * hv);
          float gv = hv * __builtin_amdgcn_rcpf(1.0f + __expf(-targ));
          hw[r * 70 + nt * 16 + l15] = f2bf(gv);
        }
    WAVE_LDS_FENCE();
#pragma unroll
    for (int ks = 0; ks < 2; ++ks) {
      bf16x8 a2[2];
#pragma unroll
      for (int mt = 0; mt < 2; ++mt)
        a2[mt] = *(const bf16x8*)(&hw[(mt * 16 + l15) * 70 + ks * 32 + lhi * 8]);
#pragma unroll
      for (int nt = 0; nt < 8; ++nt) {
        bf16x8 bfr = *(const bf16x8*)(&wsB[(nt * 16 + l15) * 68 + ks * 32 + lhi * 8]);
#pragma unroll
        for (int mt = 0; mt < 2; ++mt)
          oacc[mt][nt] = MFMA(a2[mt], bfr, oacc[mt][nt]);
      }
    }
    WAVE_LDS_FENCE();
    __syncthreads();
  }
#pragma unroll
  for (int mt = 0; mt < 2; ++mt)
#pragma unroll
    for (int nt = 0; nt < 8; ++nt)
#pragma unroll
      for (int j = 0; j < 4; ++j) {
        int r = mbase + mt * 16 + lhi * 4 + j;
        out[(size_t)r * 128 + nt * 16 + l15] = oacc[mt][nt][j] + fc2_b[nt * 16 + l15];
      }
}

// ---------------------------------------------------------------------------
extern "C" void kernel_launch(void* const* d_in, const int* in_sizes, int n_in,
                              void* d_out, int out_size, void* d_ws, size_t ws_size,
                              hipStream_t stream) {
  const float* x      = (const float*)d_in[0];
  const float* mask   = (const float*)d_in[1];
  const int*   rel    = (const int*)d_in[2];
  const float* n1g    = (const float*)d_in[3];
  const float* n1b    = (const float*)d_in[4];
  const float* qkv_w  = (const float*)d_in[5];
  const float* qkv_b  = (const float*)d_in[6];
  const float* rpb    = (const float*)d_in[7];
  const float* proj_w = (const float*)d_in[8];
  const float* proj_b = (const float*)d_in[9];
  const float* n2g    = (const float*)d_in[10];
  const float* n2b    = (const float*)d_in[11];
  const float* fc1_w  = (const float*)d_in[12];
  const float* fc1_b  = (const float*)d_in[13];
  const float* fc2_w  = (const float*)d_in[14];
  const float* fc2_b  = (const float*)d_in[15];
  float* out = (float*)d_out;

  char* ws = (char*)d_ws;
  const size_t SZ = (size_t)NTOK * 128 * 2;
  unsigned short* win   = (unsigned short*)(ws);          // ao scratch
  unsigned short* qb    = (unsigned short*)(ws + SZ);
  unsigned short* kb    = (unsigned short*)(ws + 2 * SZ);
  unsigned short* vb    = (unsigned short*)(ws + 3 * SZ);
  unsigned short* qkvT  = (unsigned short*)(ws + 4 * SZ);
  unsigned short* projT = qkvT + 384 * 128;
  unsigned short* fc1T  = projT + 128 * 128;
  unsigned short* fc2T  = fc1T + 512 * 128;
  unsigned short* cmb   = fc2T + 128 * 512;     // 4*8*9604 bf16 = 614 KB
  float* qbb            = (float*)(cmb + (size_t)4 * 8 * NN);
  unsigned short* ao = win;
  unsigned short* zb = qb;

  k0_prep<<<256, 256, 0, stream>>>(qkv_w, proj_w, fc1_w, fc2_w, n1g, n1b, qkv_b,
                                   qkvT, projT, fc1T, fc2T, qbb);
  k0b_cmb<<<(4 * 8 * NN + 255) / 256, 256, 0, stream>>>(rel, rpb, mask, cmb);
  k2_qkv<<<NTOK / 128, 256, 0, stream>>>(x, qkvT, qbb, qb, kb, vb);
  k3_attn<<<NWIN * 4, 512, 0, stream>>>(qb, kb, vb, cmb, ao);
  k4_proj_ln<<<NTOK / 128, 256, 0, stream>>>(ao, projT, proj_b, x, n2g, n2b, zb);
  k5_mlp<<<NTOK / 128, 256, 0, stream>>>(zb, fc1T, fc1_b, fc2T, fc2_b, out);
}